// Round 1
// baseline (1382.652 us; speedup 1.0000x reference)
//
#include <hip/hip_runtime.h>
#include <stdint.h>

#define NN 100000
#define NE 1600000
#define DD 128
#define NG 128

using f32x4  = __attribute__((ext_vector_type(4))) float;
using bf16x8 = __attribute__((ext_vector_type(8))) __bf16;

__device__ __forceinline__ unsigned short f2bf(float f) {
  unsigned int u = __builtin_bit_cast(unsigned int, f);
  u = (u + 0x7FFFu + ((u >> 16) & 1u)) >> 16;
  return (unsigned short)u;
}

union ABu { uint4 q; bf16x8 v; };

// ---------------- CSR build ----------------
__global__ void k_count(const int* __restrict__ dst, int* __restrict__ deg) {
  int e = blockIdx.x * 256 + threadIdx.x;
  if (e < NE) atomicAdd(&deg[dst[e]], 1);
}

__global__ __launch_bounds__(1024) void k_scan(const int* __restrict__ deg,
                                               int* __restrict__ rowptr) {
  __shared__ int lds[1024];
  const int tid = threadIdx.x;
  int carry = 0;
  for (int base = 0; base <= NN; base += 4096) {
    int idx = base + tid * 4;
    int v0 = (idx + 0 < NN) ? deg[idx + 0] : 0;
    int v1 = (idx + 1 < NN) ? deg[idx + 1] : 0;
    int v2 = (idx + 2 < NN) ? deg[idx + 2] : 0;
    int v3 = (idx + 3 < NN) ? deg[idx + 3] : 0;
    int tsum = v0 + v1 + v2 + v3;
    lds[tid] = tsum;
    __syncthreads();
    for (int off = 1; off < 1024; off <<= 1) {
      int addv = (tid >= off) ? lds[tid - off] : 0;
      __syncthreads();
      lds[tid] += addv;
      __syncthreads();
    }
    int excl = (tid ? lds[tid - 1] : 0) + carry;
    int total = lds[1023];
    __syncthreads();
    if (idx     <= NN) rowptr[idx]     = excl;
    if (idx + 1 <= NN) rowptr[idx + 1] = excl + v0;
    if (idx + 2 <= NN) rowptr[idx + 2] = excl + v0 + v1;
    if (idx + 3 <= NN) rowptr[idx + 3] = excl + v0 + v1 + v2;
    carry += total;
  }
}

__global__ void k_fill(const int* __restrict__ src, const int* __restrict__ dst,
                       const int* __restrict__ rowptr, int* __restrict__ cursor,
                       int* __restrict__ csr) {
  int e = blockIdx.x * 256 + threadIdx.x;
  if (e < NE) {
    int d = dst[e];
    int pos = rowptr[d] + atomicAdd(&cursor[d], 1);
    csr[pos] = src[e];
  }
}

// ---------------- weight transpose + bf16 convert ----------------
__global__ void k_wconv(const float* __restrict__ w0, const float* __restrict__ w1,
                        const float* __restrict__ w2, const float* __restrict__ w3,
                        const float* __restrict__ w4, const float* __restrict__ w5,
                        unsigned short* __restrict__ wt) {
  int idx = blockIdx.x * 256 + threadIdx.x;
  if (idx >= 6 * 16384) return;
  int m = idx >> 14, rem = idx & 16383;
  int n = rem >> 7, k = rem & 127;
  const float* W = (m == 0) ? w0 : (m == 1) ? w1 : (m == 2) ? w2
                 : (m == 3) ? w3 : (m == 4) ? w4 : w5;
  wt[idx] = f2bf(W[k * 128 + n]);   // wt[m][n][k] = W[k][n]
}

// ---------------- aggregation: t[i] = bf16(h[i] + sum_{j->i} h[src]) ----------------
__global__ void k_aggregate(const float* __restrict__ hin,
                            const int* __restrict__ rowptr,
                            const int* __restrict__ csr,
                            unsigned short* __restrict__ tout) {
  const int wid  = threadIdx.x >> 6;
  const int lane = threadIdx.x & 63;
  const int i = blockIdx.x * 4 + wid;
  if (i >= NN) return;
  const float2* rowi = (const float2*)(hin + i * DD);
  float2 acc = rowi[lane];
  const int beg = rowptr[i], end = rowptr[i + 1];
  for (int j = beg; j < end; ++j) {
    int s = csr[j];
    float2 v = ((const float2*)(hin + s * DD))[lane];
    acc.x += v.x; acc.y += v.y;
  }
  unsigned int packed = (unsigned int)f2bf(acc.x) | ((unsigned int)f2bf(acc.y) << 16);
  ((unsigned int*)(tout + i * DD))[lane] = packed;
}

// ---------------- fused MLP: hout = ReLU(t@W1+b1)@W2 + b2 ----------------
#define USTRIDE 136   // bf16 elems per LDS row: 272B = 16B aligned, ~2-way conflicts

__global__ __launch_bounds__(256) void k_mlp(const unsigned short* __restrict__ t,
                                             const unsigned short* __restrict__ w1t,
                                             const float* __restrict__ b1,
                                             const unsigned short* __restrict__ w2t,
                                             const float* __restrict__ b2,
                                             float* __restrict__ hout) {
  __shared__ unsigned short ulds[4][16 * USTRIDE];
  const int wid  = threadIdx.x >> 6;
  const int lane = threadIdx.x & 63;
  const int r16  = lane & 15;   // A row / B col / D col
  const int kg   = lane >> 4;   // k-group
  const int rowBase = blockIdx.x * 64 + wid * 16;

  f32x4 acc[8];
  #pragma unroll
  for (int nb = 0; nb < 8; ++nb) acc[nb] = (f32x4){0.f, 0.f, 0.f, 0.f};

  // GEMM1: u = t @ W1
  const int arow = rowBase + r16;
  const bool aval = arow < NN;
  #pragma unroll
  for (int s = 0; s < 4; ++s) {
    ABu au; au.v = (bf16x8)(__bf16)0.0f;
    if (aval) au.q = *(const uint4*)(t + arow * DD + s * 32 + kg * 8);
    #pragma unroll
    for (int nb = 0; nb < 8; ++nb) {
      ABu bu; bu.q = *(const uint4*)(w1t + (nb * 16 + r16) * DD + s * 32 + kg * 8);
      acc[nb] = __builtin_amdgcn_mfma_f32_16x16x32_bf16(au.v, bu.v, acc[nb], 0, 0, 0);
    }
  }

  // epilogue 1: bias + ReLU + bf16 -> per-wave LDS (transpose)
  unsigned short* myu = ulds[wid];
  #pragma unroll
  for (int nb = 0; nb < 8; ++nb) {
    int n = nb * 16 + r16;
    float bias = b1[n];
    #pragma unroll
    for (int reg = 0; reg < 4; ++reg) {
      int urow = kg * 4 + reg;
      float v = acc[nb][reg] + bias;
      v = v > 0.f ? v : 0.f;
      myu[urow * USTRIDE + n] = f2bf(v);
    }
  }
  __syncthreads();

  // GEMM2: hout = u @ W2
  #pragma unroll
  for (int nb = 0; nb < 8; ++nb) acc[nb] = (f32x4){0.f, 0.f, 0.f, 0.f};
  #pragma unroll
  for (int s = 0; s < 4; ++s) {
    ABu au; au.q = *(const uint4*)(myu + r16 * USTRIDE + s * 32 + kg * 8);
    #pragma unroll
    for (int nb = 0; nb < 8; ++nb) {
      ABu bu; bu.q = *(const uint4*)(w2t + (nb * 16 + r16) * DD + s * 32 + kg * 8);
      acc[nb] = __builtin_amdgcn_mfma_f32_16x16x32_bf16(au.v, bu.v, acc[nb], 0, 0, 0);
    }
  }

  // epilogue 2: bias + store fp32
  #pragma unroll
  for (int reg = 0; reg < 4; ++reg) {
    int row = rowBase + kg * 4 + reg;
    if (row < NN) {
      #pragma unroll
      for (int nb = 0; nb < 8; ++nb) {
        int n = nb * 16 + r16;
        hout[row * DD + n] = acc[nb][reg] + b2[n];
      }
    }
  }
}

// ---------------- pooling (batch is sorted) ----------------
__global__ void k_poolsum(const float* __restrict__ h, const int* __restrict__ batch,
                          float* __restrict__ sums) {
  const int f = threadIdx.x;  // 128
  int start = blockIdx.x * 256;
  int end = min(start + 256, NN);
  float acc = 0.f;
  int cur = batch[start];
  for (int i = start; i < end; ++i) {
    int b = batch[i];
    if (b != cur) { atomicAdd(&sums[cur * DD + f], acc); acc = 0.f; cur = b; }
    acc += h[i * DD + f];
  }
  atomicAdd(&sums[cur * DD + f], acc);
}

__global__ void k_cnt(const int* __restrict__ batch, int* __restrict__ cnt) {
  int i = blockIdx.x * 256 + threadIdx.x;
  if (i < NN) atomicAdd(&cnt[batch[i]], 1);
}

__global__ void k_finalize(const float* __restrict__ sums, const int* __restrict__ cnt,
                           float* __restrict__ out) {
  int g = blockIdx.x, f = threadIdx.x;
  float c = (float)max(cnt[g], 1);
  out[g * DD + f] = sums[g * DD + f] / c;
}

// ---------------- launch ----------------
extern "C" void kernel_launch(void* const* d_in, const int* in_sizes, int n_in,
                              void* d_out, int out_size, void* d_ws, size_t ws_size,
                              hipStream_t stream) {
  const float* x    = (const float*)d_in[0];
  const int* ei     = (const int*)d_in[1];
  const int* src    = ei;
  const int* dst    = ei + NE;
  const int* batch  = (const int*)d_in[2];

  char* ws = (char*)d_ws;
  size_t off = 0;
  auto alloc = [&](size_t bytes) { char* p = ws + off; off = (off + bytes + 255) & ~(size_t)255; return p; };

  int*  deg    = (int*)alloc(2 * NN * 4);       // deg + cursor contiguous
  int*  cursor = deg + NN;
  int*  rowptr = (int*)alloc((NN + 1) * 4);
  int*  csr    = (int*)alloc(NE * 4);
  unsigned short* wt = (unsigned short*)alloc(6 * 16384 * 2);
  unsigned short* t  = (unsigned short*)alloc((size_t)NN * DD * 2);
  float* hA    = (float*)alloc((size_t)NN * DD * 4);
  float* hB    = (float*)alloc((size_t)NN * DD * 4);
  float* sums  = (float*)alloc(NG * DD * 4 + NG * 4);   // sums + cnt contiguous
  int*   cnt   = (int*)(sums + NG * DD);

  hipMemsetAsync(deg, 0, 2 * NN * 4, stream);
  hipMemsetAsync(sums, 0, NG * DD * 4 + NG * 4, stream);

  k_wconv<<<(6 * 16384 + 255) / 256, 256, 0, stream>>>(
      (const float*)d_in[3], (const float*)d_in[5],
      (const float*)d_in[7], (const float*)d_in[9],
      (const float*)d_in[11], (const float*)d_in[13], wt);

  k_count<<<(NE + 255) / 256, 256, 0, stream>>>(dst, deg);
  k_scan<<<1, 1024, 0, stream>>>(deg, rowptr);
  k_fill<<<(NE + 255) / 256, 256, 0, stream>>>(src, dst, rowptr, cursor, csr);

  const float* hin = x;
  float* houts[3] = {hA, hB, hA};
  for (int l = 0; l < 3; ++l) {
    k_aggregate<<<NN / 4, 256, 0, stream>>>(hin, rowptr, csr, t);
    k_mlp<<<(NN + 63) / 64, 256, 0, stream>>>(
        t, wt + (2 * l) * 16384, (const float*)d_in[4 + 4 * l],
        wt + (2 * l + 1) * 16384, (const float*)d_in[6 + 4 * l], houts[l]);
    hin = houts[l];
  }

  k_poolsum<<<(NN + 255) / 256, 128, 0, stream>>>(hin, batch, sums);
  k_cnt<<<(NN + 255) / 256, 256, 0, stream>>>(batch, cnt);
  k_finalize<<<NG, 128, 0, stream>>>(sums, cnt, (float*)d_out);
}

// Round 2
// 1122.010 us; speedup vs baseline: 1.2323x; 1.2323x over previous
//
#include <hip/hip_runtime.h>
#include <stdint.h>

#define NN 100000
#define NE 1600000
#define DD 128
#define NG 128

using f32x4  = __attribute__((ext_vector_type(4))) float;
using bf16x8 = __attribute__((ext_vector_type(8))) __bf16;

__device__ __forceinline__ unsigned short f2bf(float f) {
  unsigned int u = __builtin_bit_cast(unsigned int, f);
  u = (u + 0x7FFFu + ((u >> 16) & 1u)) >> 16;
  return (unsigned short)u;
}

union ABu { uint4 q; bf16x8 v; };

// ---------------- CSR build ----------------
__global__ void k_count(const int* __restrict__ dst, int* __restrict__ deg) {
  int e = blockIdx.x * 256 + threadIdx.x;
  if (e < NE) atomicAdd(&deg[dst[e]], 1);
}

__global__ __launch_bounds__(1024) void k_scan(const int* __restrict__ deg,
                                               int* __restrict__ rowptr) {
  __shared__ int lds[1024];
  const int tid = threadIdx.x;
  int carry = 0;
  for (int base = 0; base <= NN; base += 4096) {
    int idx = base + tid * 4;
    int v0 = (idx + 0 < NN) ? deg[idx + 0] : 0;
    int v1 = (idx + 1 < NN) ? deg[idx + 1] : 0;
    int v2 = (idx + 2 < NN) ? deg[idx + 2] : 0;
    int v3 = (idx + 3 < NN) ? deg[idx + 3] : 0;
    int tsum = v0 + v1 + v2 + v3;
    lds[tid] = tsum;
    __syncthreads();
    for (int off = 1; off < 1024; off <<= 1) {
      int addv = (tid >= off) ? lds[tid - off] : 0;
      __syncthreads();
      lds[tid] += addv;
      __syncthreads();
    }
    int excl = (tid ? lds[tid - 1] : 0) + carry;
    int total = lds[1023];
    __syncthreads();
    if (idx     <= NN) rowptr[idx]     = excl;
    if (idx + 1 <= NN) rowptr[idx + 1] = excl + v0;
    if (idx + 2 <= NN) rowptr[idx + 2] = excl + v0 + v1;
    if (idx + 3 <= NN) rowptr[idx + 3] = excl + v0 + v1 + v2;
    carry += total;
  }
}

__global__ void k_fill(const int* __restrict__ src, const int* __restrict__ dst,
                       const int* __restrict__ rowptr, int* __restrict__ cursor,
                       int* __restrict__ csr) {
  int e = blockIdx.x * 256 + threadIdx.x;
  if (e < NE) {
    int d = dst[e];
    int pos = rowptr[d] + atomicAdd(&cursor[d], 1);
    csr[pos] = src[e];
  }
}

// ---------------- weight transpose + bf16 convert ----------------
__global__ void k_wconv(const float* __restrict__ w0, const float* __restrict__ w1,
                        const float* __restrict__ w2, const float* __restrict__ w3,
                        const float* __restrict__ w4, const float* __restrict__ w5,
                        unsigned short* __restrict__ wt) {
  int idx = blockIdx.x * 256 + threadIdx.x;
  if (idx >= 6 * 16384) return;
  int m = idx >> 14, rem = idx & 16383;
  int n = rem >> 7, k = rem & 127;
  const float* W = (m == 0) ? w0 : (m == 1) ? w1 : (m == 2) ? w2
                 : (m == 3) ? w3 : (m == 4) ? w4 : w5;
  wt[idx] = f2bf(W[k * 128 + n]);   // wt[m][n][k] = W[k][n]
}

// ---------------- aggregation: t[i] = bf16(h[i] + sum_{j->i} h[src]) ----------------
__global__ void k_aggregate(const float* __restrict__ hin,
                            const int* __restrict__ rowptr,
                            const int* __restrict__ csr,
                            unsigned short* __restrict__ tout) {
  const int wid  = threadIdx.x >> 6;
  const int lane = threadIdx.x & 63;
  const int i = blockIdx.x * 4 + wid;
  if (i >= NN) return;
  const float2* rowi = (const float2*)(hin + i * DD);
  float2 acc = rowi[lane];
  const int beg = rowptr[i], end = rowptr[i + 1];
  for (int j = beg; j < end; ++j) {
    int s = csr[j];
    float2 v = ((const float2*)(hin + s * DD))[lane];
    acc.x += v.x; acc.y += v.y;
  }
  unsigned int packed = (unsigned int)f2bf(acc.x) | ((unsigned int)f2bf(acc.y) << 16);
  ((unsigned int*)(tout + i * DD))[lane] = packed;
}

// ---------------- fused MLP: hout = ReLU(t@W1+b1)@W2 + b2 ----------------
#define USTRIDE 136   // bf16 elems per LDS row: 272B = 16B aligned, ~2-way conflicts

__global__ __launch_bounds__(256) void k_mlp(const unsigned short* __restrict__ t,
                                             const unsigned short* __restrict__ w1t,
                                             const float* __restrict__ b1,
                                             const unsigned short* __restrict__ w2t,
                                             const float* __restrict__ b2,
                                             float* __restrict__ hout) {
  __shared__ unsigned short ulds[4][16 * USTRIDE];
  const int wid  = threadIdx.x >> 6;
  const int lane = threadIdx.x & 63;
  const int r16  = lane & 15;   // A row / B col / D col
  const int kg   = lane >> 4;   // k-group
  const int rowBase = blockIdx.x * 64 + wid * 16;

  f32x4 acc[8];
  #pragma unroll
  for (int nb = 0; nb < 8; ++nb) acc[nb] = (f32x4){0.f, 0.f, 0.f, 0.f};

  // GEMM1: u = t @ W1
  const int arow = rowBase + r16;
  const bool aval = arow < NN;
  #pragma unroll
  for (int s = 0; s < 4; ++s) {
    ABu au; au.v = (bf16x8)(__bf16)0.0f;
    if (aval) au.q = *(const uint4*)(t + arow * DD + s * 32 + kg * 8);
    #pragma unroll
    for (int nb = 0; nb < 8; ++nb) {
      ABu bu; bu.q = *(const uint4*)(w1t + (nb * 16 + r16) * DD + s * 32 + kg * 8);
      acc[nb] = __builtin_amdgcn_mfma_f32_16x16x32_bf16(au.v, bu.v, acc[nb], 0, 0, 0);
    }
  }

  // epilogue 1: bias + ReLU + bf16 -> per-wave LDS (transpose)
  unsigned short* myu = ulds[wid];
  #pragma unroll
  for (int nb = 0; nb < 8; ++nb) {
    int n = nb * 16 + r16;
    float bias = b1[n];
    #pragma unroll
    for (int reg = 0; reg < 4; ++reg) {
      int urow = kg * 4 + reg;
      float v = acc[nb][reg] + bias;
      v = v > 0.f ? v : 0.f;
      myu[urow * USTRIDE + n] = f2bf(v);
    }
  }
  __syncthreads();

  // GEMM2: hout = u @ W2
  #pragma unroll
  for (int nb = 0; nb < 8; ++nb) acc[nb] = (f32x4){0.f, 0.f, 0.f, 0.f};
  #pragma unroll
  for (int s = 0; s < 4; ++s) {
    ABu au; au.q = *(const uint4*)(myu + r16 * USTRIDE + s * 32 + kg * 8);
    #pragma unroll
    for (int nb = 0; nb < 8; ++nb) {
      ABu bu; bu.q = *(const uint4*)(w2t + (nb * 16 + r16) * DD + s * 32 + kg * 8);
      acc[nb] = __builtin_amdgcn_mfma_f32_16x16x32_bf16(au.v, bu.v, acc[nb], 0, 0, 0);
    }
  }

  // epilogue 2: bias + store fp32
  #pragma unroll
  for (int reg = 0; reg < 4; ++reg) {
    int row = rowBase + kg * 4 + reg;
    if (row < NN) {
      #pragma unroll
      for (int nb = 0; nb < 8; ++nb) {
        int n = nb * 16 + r16;
        hout[row * DD + n] = acc[nb][reg] + b2[n];
      }
    }
  }
}

// ---------------- pooling (batch is sorted) ----------------
__global__ void k_poolsum(const float* __restrict__ h, const int* __restrict__ batch,
                          float* __restrict__ sums) {
  const int f = threadIdx.x;  // 128
  int start = blockIdx.x * 256;
  int end = min(start + 256, NN);
  float acc = 0.f;
  int cur = batch[start];
  for (int i = start; i < end; ++i) {
    int b = batch[i];
    if (b != cur) { atomicAdd(&sums[cur * DD + f], acc); acc = 0.f; cur = b; }
    acc += h[i * DD + f];
  }
  atomicAdd(&sums[cur * DD + f], acc);
}

// counts via binary search on the SORTED batch array — no atomics.
__global__ void k_bounds(const int* __restrict__ batch, int* __restrict__ cnt) {
  int g = threadIdx.x;  // 128 threads, one block
  int lo = 0, hi = NN;
  while (lo < hi) { int mid = (lo + hi) >> 1; if (batch[mid] < g) lo = mid + 1; else hi = mid; }
  int s = lo;
  hi = NN;
  while (lo < hi) { int mid = (lo + hi) >> 1; if (batch[mid] < g + 1) lo = mid + 1; else hi = mid; }
  cnt[g] = lo - s;
}

__global__ void k_finalize(const float* __restrict__ sums, const int* __restrict__ cnt,
                           float* __restrict__ out) {
  int g = blockIdx.x, f = threadIdx.x;
  float c = (float)max(cnt[g], 1);
  out[g * DD + f] = sums[g * DD + f] / c;
}

// ---------------- launch ----------------
extern "C" void kernel_launch(void* const* d_in, const int* in_sizes, int n_in,
                              void* d_out, int out_size, void* d_ws, size_t ws_size,
                              hipStream_t stream) {
  const float* x    = (const float*)d_in[0];
  const int* ei     = (const int*)d_in[1];
  const int* src    = ei;
  const int* dst    = ei + NE;
  const int* batch  = (const int*)d_in[2];

  char* ws = (char*)d_ws;
  size_t off = 0;
  auto alloc = [&](size_t bytes) { char* p = ws + off; off = (off + bytes + 255) & ~(size_t)255; return p; };

  int*  deg    = (int*)alloc(2 * NN * 4);       // deg + cursor contiguous
  int*  cursor = deg + NN;
  int*  rowptr = (int*)alloc((NN + 1) * 4);
  int*  csr    = (int*)alloc(NE * 4);
  unsigned short* wt = (unsigned short*)alloc(6 * 16384 * 2);
  unsigned short* t  = (unsigned short*)alloc((size_t)NN * DD * 2);
  float* hA    = (float*)alloc((size_t)NN * DD * 4);
  float* hB    = (float*)alloc((size_t)NN * DD * 4);
  float* sums  = (float*)alloc(NG * DD * 4 + NG * 4);   // sums + cnt contiguous
  int*   cnt   = (int*)(sums + NG * DD);

  hipMemsetAsync(deg, 0, 2 * NN * 4, stream);
  hipMemsetAsync(sums, 0, NG * DD * 4 + NG * 4, stream);

  k_wconv<<<(6 * 16384 + 255) / 256, 256, 0, stream>>>(
      (const float*)d_in[3], (const float*)d_in[5],
      (const float*)d_in[7], (const float*)d_in[9],
      (const float*)d_in[11], (const float*)d_in[13], wt);

  k_count<<<(NE + 255) / 256, 256, 0, stream>>>(dst, deg);
  k_scan<<<1, 1024, 0, stream>>>(deg, rowptr);
  k_fill<<<(NE + 255) / 256, 256, 0, stream>>>(src, dst, rowptr, cursor, csr);

  const float* hin = x;
  float* houts[3] = {hA, hB, hA};
  for (int l = 0; l < 3; ++l) {
    k_aggregate<<<NN / 4, 256, 0, stream>>>(hin, rowptr, csr, t);
    k_mlp<<<(NN + 63) / 64, 256, 0, stream>>>(
        t, wt + (2 * l) * 16384, (const float*)d_in[4 + 4 * l],
        wt + (2 * l + 1) * 16384, (const float*)d_in[6 + 4 * l], houts[l]);
    hin = houts[l];
  }

  k_poolsum<<<(NN + 255) / 256, 128, 0, stream>>>(hin, batch, sums);
  k_bounds<<<1, 128, 0, stream>>>(batch, cnt);
  k_finalize<<<NG, 128, 0, stream>>>(sums, cnt, (float*)d_out);
}

// Round 5
// 819.260 us; speedup vs baseline: 1.6877x; 1.3695x over previous
//
#include <hip/hip_runtime.h>
#include <stdint.h>

#define NN 100000
#define NE 1600000
#define DD 128
#define NG 128

using f32x4  = __attribute__((ext_vector_type(4))) float;
using bf16x8 = __attribute__((ext_vector_type(8))) __bf16;

__device__ __forceinline__ unsigned short f2bf(float f) {
  unsigned int u = __builtin_bit_cast(unsigned int, f);
  u = (u + 0x7FFFu + ((u >> 16) & 1u)) >> 16;
  return (unsigned short)u;
}

__device__ __forceinline__ float2 bfu(unsigned int u) {
  float2 r;
  r.x = __builtin_bit_cast(float, u << 16);
  r.y = __builtin_bit_cast(float, u & 0xffff0000u);
  return r;
}

union ABu { uint4 q; bf16x8 v; };

// ---------------- CSR build ----------------
__global__ void k_count(const int* __restrict__ dst, int* __restrict__ deg) {
  int e = blockIdx.x * 256 + threadIdx.x;
  if (e < NE) atomicAdd(&deg[dst[e]], 1);
}

__global__ __launch_bounds__(1024) void k_scan(const int* __restrict__ deg,
                                               int* __restrict__ rowptr) {
  __shared__ int wsum[16];
  const int tid = threadIdx.x, wid = tid >> 6, lane = tid & 63;
  int carry = 0;
  for (int base = 0; base <= NN; base += 4096) {
    int idx = base + tid * 4;
    int v0 = (idx + 0 < NN) ? deg[idx + 0] : 0;
    int v1 = (idx + 1 < NN) ? deg[idx + 1] : 0;
    int v2 = (idx + 2 < NN) ? deg[idx + 2] : 0;
    int v3 = (idx + 3 < NN) ? deg[idx + 3] : 0;
    int tsum = v0 + v1 + v2 + v3;
    // inclusive wave scan
    int sc = tsum;
    #pragma unroll
    for (int off = 1; off < 64; off <<= 1) {
      int n = __shfl_up(sc, off);
      if (lane >= off) sc += n;
    }
    if (lane == 63) wsum[wid] = sc;
    __syncthreads();
    if (wid == 0 && lane < 16) {
      int w = wsum[lane];
      #pragma unroll
      for (int off = 1; off < 16; off <<= 1) {
        int n = __shfl_up(w, off);
        if (lane >= off) w += n;
      }
      wsum[lane] = w;
    }
    __syncthreads();
    int woff = (wid ? wsum[wid - 1] : 0) + carry;
    int total = wsum[15];
    int excl = woff + sc - tsum;
    if (idx     <= NN) rowptr[idx]     = excl;
    if (idx + 1 <= NN) rowptr[idx + 1] = excl + v0;
    if (idx + 2 <= NN) rowptr[idx + 2] = excl + v0 + v1;
    if (idx + 3 <= NN) rowptr[idx + 3] = excl + v0 + v1 + v2;
    __syncthreads();   // wsum reused next iteration
    carry += total;
  }
}

__global__ void k_fill(const int* __restrict__ src, const int* __restrict__ dst,
                       const int* __restrict__ rowptr, int* __restrict__ cursor,
                       int* __restrict__ csr) {
  int e = blockIdx.x * 256 + threadIdx.x;
  if (e < NE) {
    int d = dst[e];
    int pos = rowptr[d] + atomicAdd(&cursor[d], 1);
    csr[pos] = src[e];
  }
}

// ---------------- weight transpose + bf16 convert ----------------
__global__ void k_wconv(const float* __restrict__ w0, const float* __restrict__ w1,
                        const float* __restrict__ w2, const float* __restrict__ w3,
                        const float* __restrict__ w4, const float* __restrict__ w5,
                        unsigned short* __restrict__ wt) {
  int idx = blockIdx.x * 256 + threadIdx.x;
  if (idx >= 6 * 16384) return;
  int m = idx >> 14, rem = idx & 16383;
  int n = rem >> 7, k = rem & 127;
  const float* W = (m == 0) ? w0 : (m == 1) ? w1 : (m == 2) ? w2
                 : (m == 3) ? w3 : (m == 4) ? w4 : w5;
  wt[idx] = f2bf(W[k * 128 + n]);   // wt[m][n][k] = W[k][n]
}

// ---------------- x -> bf16 ----------------
__global__ void k_xconv(const float* __restrict__ x, unsigned short* __restrict__ xb) {
  int i = blockIdx.x * 256 + threadIdx.x;   // one float4 per thread
  if (i >= NN * DD / 4) return;
  float4 v = ((const float4*)x)[i];
  uint2 p;
  p.x = (unsigned int)f2bf(v.x) | ((unsigned int)f2bf(v.y) << 16);
  p.y = (unsigned int)f2bf(v.z) | ((unsigned int)f2bf(v.w) << 16);
  ((uint2*)xb)[i] = p;
}

// ---------------- aggregation: t[i] = bf16(h[i] + sum_{j->i} h[src]) ----------------
__global__ void k_aggregate(const unsigned short* __restrict__ hb,
                            const int* __restrict__ rowptr,
                            const int* __restrict__ csr,
                            unsigned short* __restrict__ tout) {
  const int wid  = threadIdx.x >> 6;
  const int lane = threadIdx.x & 63;
  const int i = blockIdx.x * 4 + wid;
  if (i >= NN) return;
  const unsigned int* h32 = (const unsigned int*)hb;
  float2 acc = bfu(h32[i * 64 + lane]);
  const int beg = rowptr[i], end = rowptr[i + 1];
  int j = beg;
  for (; j + 3 < end; j += 4) {
    int s0 = csr[j], s1 = csr[j + 1], s2 = csr[j + 2], s3 = csr[j + 3];
    unsigned int v0 = h32[s0 * 64 + lane];
    unsigned int v1 = h32[s1 * 64 + lane];
    unsigned int v2 = h32[s2 * 64 + lane];
    unsigned int v3 = h32[s3 * 64 + lane];
    float2 a0 = bfu(v0), a1 = bfu(v1), a2 = bfu(v2), a3 = bfu(v3);
    acc.x += (a0.x + a1.x) + (a2.x + a3.x);
    acc.y += (a0.y + a1.y) + (a2.y + a3.y);
  }
  for (; j < end; ++j) {
    float2 a = bfu(h32[csr[j] * 64 + lane]);
    acc.x += a.x; acc.y += a.y;
  }
  ((unsigned int*)tout)[i * 64 + lane] =
      (unsigned int)f2bf(acc.x) | ((unsigned int)f2bf(acc.y) << 16);
}

// ---------------- fused MLP: hout = bf16(ReLU(t@W1+b1)@W2 + b2) ----------------
#define USTRIDE 136   // bf16 elems per LDS row: 272B = 16B aligned, ~2-way conflicts

__global__ __launch_bounds__(256) void k_mlp(const unsigned short* __restrict__ t,
                                             const unsigned short* __restrict__ w1t,
                                             const float* __restrict__ b1,
                                             const unsigned short* __restrict__ w2t,
                                             const float* __restrict__ b2,
                                             unsigned short* __restrict__ hout) {
  __shared__ unsigned short ulds[4][16 * USTRIDE];
  const int wid  = threadIdx.x >> 6;
  const int lane = threadIdx.x & 63;
  const int r16  = lane & 15;   // A row / B col / D col
  const int kg   = lane >> 4;   // k-group
  const int rowBase = blockIdx.x * 64 + wid * 16;

  f32x4 acc[8];
  #pragma unroll
  for (int nb = 0; nb < 8; ++nb) acc[nb] = (f32x4){0.f, 0.f, 0.f, 0.f};

  // GEMM1: u = t @ W1
  const int arow = rowBase + r16;
  const bool aval = arow < NN;
  #pragma unroll
  for (int s = 0; s < 4; ++s) {
    ABu au; au.v = (bf16x8)(__bf16)0.0f;
    if (aval) au.q = *(const uint4*)(t + arow * DD + s * 32 + kg * 8);
    #pragma unroll
    for (int nb = 0; nb < 8; ++nb) {
      ABu bu; bu.q = *(const uint4*)(w1t + (nb * 16 + r16) * DD + s * 32 + kg * 8);
      acc[nb] = __builtin_amdgcn_mfma_f32_16x16x32_bf16(au.v, bu.v, acc[nb], 0, 0, 0);
    }
  }

  // epilogue 1: bias + ReLU + bf16 -> per-wave LDS (transpose)
  unsigned short* myu = ulds[wid];
  #pragma unroll
  for (int nb = 0; nb < 8; ++nb) {
    int n = nb * 16 + r16;
    float bias = b1[n];
    #pragma unroll
    for (int reg = 0; reg < 4; ++reg) {
      int urow = kg * 4 + reg;
      float v = acc[nb][reg] + bias;
      v = v > 0.f ? v : 0.f;
      myu[urow * USTRIDE + n] = f2bf(v);
    }
  }
  __syncthreads();

  // GEMM2: hout = u @ W2
  #pragma unroll
  for (int nb = 0; nb < 8; ++nb) acc[nb] = (f32x4){0.f, 0.f, 0.f, 0.f};
  #pragma unroll
  for (int s = 0; s < 4; ++s) {
    ABu au; au.q = *(const uint4*)(myu + r16 * USTRIDE + s * 32 + kg * 8);
    #pragma unroll
    for (int nb = 0; nb < 8; ++nb) {
      ABu bu; bu.q = *(const uint4*)(w2t + (nb * 16 + r16) * DD + s * 32 + kg * 8);
      acc[nb] = __builtin_amdgcn_mfma_f32_16x16x32_bf16(au.v, bu.v, acc[nb], 0, 0, 0);
    }
  }

  // epilogue 2: bias + store bf16
  #pragma unroll
  for (int reg = 0; reg < 4; ++reg) {
    int row = rowBase + kg * 4 + reg;
    if (row < NN) {
      #pragma unroll
      for (int nb = 0; nb < 8; ++nb) {
        int n = nb * 16 + r16;
        hout[row * DD + n] = f2bf(acc[nb][reg] + b2[n]);
      }
    }
  }
}

// ---------------- pooling (batch is sorted) ----------------
__global__ void k_poolsum(const unsigned short* __restrict__ hb,
                          const int* __restrict__ batch,
                          float* __restrict__ sums) {
  const int t = threadIdx.x;  // 64: thread t owns feats 2t, 2t+1
  const unsigned int* h32 = (const unsigned int*)hb;
  int start = blockIdx.x * 256;
  int end = min(start + 256, NN);
  float2 acc = {0.f, 0.f};
  int cur = batch[start];
  for (int i = start; i < end; ++i) {
    int b = batch[i];
    if (b != cur) {
      atomicAdd(&sums[cur * DD + 2 * t], acc.x);
      atomicAdd(&sums[cur * DD + 2 * t + 1], acc.y);
      acc.x = 0.f; acc.y = 0.f; cur = b;
    }
    float2 v = bfu(h32[i * 64 + t]);
    acc.x += v.x; acc.y += v.y;
  }
  atomicAdd(&sums[cur * DD + 2 * t], acc.x);
  atomicAdd(&sums[cur * DD + 2 * t + 1], acc.y);
}

// counts via binary search on the SORTED batch array — no atomics.
__global__ void k_bounds(const int* __restrict__ batch, int* __restrict__ cnt) {
  int g = threadIdx.x;  // 128 threads, one block
  int lo = 0, hi = NN;
  while (lo < hi) { int mid = (lo + hi) >> 1; if (batch[mid] < g) lo = mid + 1; else hi = mid; }
  int s = lo;
  hi = NN;
  while (lo < hi) { int mid = (lo + hi) >> 1; if (batch[mid] < g + 1) lo = mid + 1; else hi = mid; }
  cnt[g] = lo - s;
}

__global__ void k_finalize(const float* __restrict__ sums, const int* __restrict__ cnt,
                           float* __restrict__ out) {
  int g = blockIdx.x, f = threadIdx.x;
  float c = (float)max(cnt[g], 1);
  out[g * DD + f] = sums[g * DD + f] / c;
}

// ---------------- launch ----------------
extern "C" void kernel_launch(void* const* d_in, const int* in_sizes, int n_in,
                              void* d_out, int out_size, void* d_ws, size_t ws_size,
                              hipStream_t stream) {
  const float* x    = (const float*)d_in[0];
  const int* ei     = (const int*)d_in[1];
  const int* src    = ei;
  const int* dst    = ei + NE;
  const int* batch  = (const int*)d_in[2];

  char* ws = (char*)d_ws;
  size_t off = 0;
  auto alloc = [&](size_t bytes) { char* p = ws + off; off = (off + bytes + 255) & ~(size_t)255; return p; };

  int*  deg    = (int*)alloc(2 * NN * 4);       // deg + cursor contiguous
  int*  cursor = deg + NN;
  int*  rowptr = (int*)alloc((NN + 1) * 4);
  int*  csr    = (int*)alloc(NE * 4);
  unsigned short* wt = (unsigned short*)alloc(6 * 16384 * 2);
  unsigned short* xb = (unsigned short*)alloc((size_t)NN * DD * 2);
  unsigned short* t  = (unsigned short*)alloc((size_t)NN * DD * 2);
  unsigned short* hA = (unsigned short*)alloc((size_t)NN * DD * 2);
  unsigned short* hB = (unsigned short*)alloc((size_t)NN * DD * 2);
  float* sums  = (float*)alloc(NG * DD * 4 + NG * 4);   // sums + cnt contiguous
  int*   cnt   = (int*)(sums + NG * DD);

  hipMemsetAsync(deg, 0, 2 * NN * 4, stream);
  hipMemsetAsync(sums, 0, NG * DD * 4 + NG * 4, stream);

  k_wconv<<<(6 * 16384 + 255) / 256, 256, 0, stream>>>(
      (const float*)d_in[3], (const float*)d_in[5],
      (const float*)d_in[7], (const float*)d_in[9],
      (const float*)d_in[11], (const float*)d_in[13], wt);
  k_xconv<<<(NN * DD / 4 + 255) / 256, 256, 0, stream>>>(x, xb);

  k_count<<<(NE + 255) / 256, 256, 0, stream>>>(dst, deg);
  k_scan<<<1, 1024, 0, stream>>>(deg, rowptr);
  k_fill<<<(NE + 255) / 256, 256, 0, stream>>>(src, dst, rowptr, cursor, csr);

  const unsigned short* hin = xb;
  unsigned short* houts[3] = {hA, hB, hA};
  for (int l = 0; l < 3; ++l) {
    k_aggregate<<<(NN + 3) / 4, 256, 0, stream>>>(hin, rowptr, csr, t);
    k_mlp<<<(NN + 63) / 64, 256, 0, stream>>>(
        t, wt + (2 * l) * 16384, (const float*)d_in[4 + 4 * l],
        wt + (2 * l + 1) * 16384, (const float*)d_in[6 + 4 * l], houts[l]);
    hin = houts[l];
  }

  k_poolsum<<<(NN + 255) / 256, 64, 0, stream>>>(hin, batch, sums);
  k_bounds<<<1, 128, 0, stream>>>(batch, cnt);
  k_finalize<<<NG, 128, 0, stream>>>(sums, cnt, (float*)d_out);
}

// Round 7
// 794.512 us; speedup vs baseline: 1.7403x; 1.0311x over previous
//
#include <hip/hip_runtime.h>
#include <stdint.h>

#define NN 100000
#define NE 1600000
#define DD 128
#define NG 128
#define NPX 12500   // nodes per XCD partition (8 * 12500 = 100000)

using f32x4  = __attribute__((ext_vector_type(4))) float;
using bf16x8 = __attribute__((ext_vector_type(8))) __bf16;

__device__ __forceinline__ unsigned short f2bf(float f) {
  unsigned int u = __builtin_bit_cast(unsigned int, f);
  u = (u + 0x7FFFu + ((u >> 16) & 1u)) >> 16;
  return (unsigned short)u;
}

__device__ __forceinline__ float2 bfu(unsigned int u) {
  float2 r;
  r.x = __builtin_bit_cast(float, u << 16);
  r.y = __builtin_bit_cast(float, u & 0xffff0000u);
  return r;
}

union ABu { uint4 q; bf16x8 v; };

// ---------------- CSR build (XCD-partitioned scatter) ----------------
// blocks with bid&7==k handle only dst in [k*NPX,(k+1)*NPX): deg/cursor/csr
// lines stay resident+dirty in exactly one XCD's L2 -> no cross-XCD thrash.
__global__ void k_count(const int* __restrict__ dst, int* __restrict__ deg) {
  int xcd = blockIdx.x & 7;
  int e = (blockIdx.x >> 3) * 256 + threadIdx.x;
  if (e >= NE) return;
  int d = dst[e];
  if ((unsigned)(d - xcd * NPX) < (unsigned)NPX) atomicAdd(&deg[d], 1);
}

__global__ __launch_bounds__(1024) void k_scan(const int* __restrict__ deg,
                                               int* __restrict__ rowptr) {
  __shared__ int wsum[16];
  const int tid = threadIdx.x, wid = tid >> 6, lane = tid & 63;
  int carry = 0;
  for (int base = 0; base <= NN; base += 4096) {
    int idx = base + tid * 4;
    int v0 = (idx + 0 < NN) ? deg[idx + 0] : 0;
    int v1 = (idx + 1 < NN) ? deg[idx + 1] : 0;
    int v2 = (idx + 2 < NN) ? deg[idx + 2] : 0;
    int v3 = (idx + 3 < NN) ? deg[idx + 3] : 0;
    int tsum = v0 + v1 + v2 + v3;
    // inclusive wave scan
    int sc = tsum;
    #pragma unroll
    for (int off = 1; off < 64; off <<= 1) {
      int n = __shfl_up(sc, off);
      if (lane >= off) sc += n;
    }
    if (lane == 63) wsum[wid] = sc;
    __syncthreads();
    if (wid == 0 && lane < 16) {
      int w = wsum[lane];
      #pragma unroll
      for (int off = 1; off < 16; off <<= 1) {
        int n = __shfl_up(w, off);
        if (lane >= off) w += n;
      }
      wsum[lane] = w;
    }
    __syncthreads();
    int woff = (wid ? wsum[wid - 1] : 0) + carry;
    int total = wsum[15];
    int excl = woff + sc - tsum;
    if (idx     <= NN) rowptr[idx]     = excl;
    if (idx + 1 <= NN) rowptr[idx + 1] = excl + v0;
    if (idx + 2 <= NN) rowptr[idx + 2] = excl + v0 + v1;
    if (idx + 3 <= NN) rowptr[idx + 3] = excl + v0 + v1 + v2;
    __syncthreads();   // wsum reused next iteration
    carry += total;
  }
}

__global__ void k_fill(const int* __restrict__ src, const int* __restrict__ dst,
                       const int* __restrict__ rowptr, int* __restrict__ cursor,
                       int* __restrict__ csr) {
  int xcd = blockIdx.x & 7;
  int e = (blockIdx.x >> 3) * 256 + threadIdx.x;
  if (e >= NE) return;
  int d = dst[e];
  if ((unsigned)(d - xcd * NPX) < (unsigned)NPX) {
    int pos = rowptr[d] + atomicAdd(&cursor[d], 1);
    csr[pos] = src[e];
  }
}

// ---------------- weight transpose + bf16 convert ----------------
__global__ void k_wconv(const float* __restrict__ w0, const float* __restrict__ w1,
                        const float* __restrict__ w2, const float* __restrict__ w3,
                        const float* __restrict__ w4, const float* __restrict__ w5,
                        unsigned short* __restrict__ wt) {
  int idx = blockIdx.x * 256 + threadIdx.x;
  if (idx >= 6 * 16384) return;
  int m = idx >> 14, rem = idx & 16383;
  int n = rem >> 7, k = rem & 127;
  const float* W = (m == 0) ? w0 : (m == 1) ? w1 : (m == 2) ? w2
                 : (m == 3) ? w3 : (m == 4) ? w4 : w5;
  wt[idx] = f2bf(W[k * 128 + n]);   // wt[m][n][k] = W[k][n]
}

// ---------------- x -> bf16 ----------------
__global__ void k_xconv(const float* __restrict__ x, unsigned short* __restrict__ xb) {
  int i = blockIdx.x * 256 + threadIdx.x;   // one float4 per thread
  if (i >= NN * DD / 4) return;
  float4 v = ((const float4*)x)[i];
  uint2 p;
  p.x = (unsigned int)f2bf(v.x) | ((unsigned int)f2bf(v.y) << 16);
  p.y = (unsigned int)f2bf(v.z) | ((unsigned int)f2bf(v.w) << 16);
  ((uint2*)xb)[i] = p;
}

// ---------------- aggregation: t[i] = bf16(h[i] + sum_{j->i} h[src]) ----------------
__global__ void k_aggregate(const unsigned short* __restrict__ hb,
                            const int* __restrict__ rowptr,
                            const int* __restrict__ csr,
                            unsigned short* __restrict__ tout) {
  const int wid  = threadIdx.x >> 6;
  const int lane = threadIdx.x & 63;
  const int i = blockIdx.x * 4 + wid;
  if (i >= NN) return;
  const unsigned int* h32 = (const unsigned int*)hb;
  float2 acc = bfu(h32[i * 64 + lane]);
  const int beg = rowptr[i], end = rowptr[i + 1];
  int j = beg;
  for (; j + 7 < end; j += 8) {
    int s0 = csr[j],     s1 = csr[j + 1], s2 = csr[j + 2], s3 = csr[j + 3];
    int s4 = csr[j + 4], s5 = csr[j + 5], s6 = csr[j + 6], s7 = csr[j + 7];
    unsigned int v0 = h32[s0 * 64 + lane];
    unsigned int v1 = h32[s1 * 64 + lane];
    unsigned int v2 = h32[s2 * 64 + lane];
    unsigned int v3 = h32[s3 * 64 + lane];
    unsigned int v4 = h32[s4 * 64 + lane];
    unsigned int v5 = h32[s5 * 64 + lane];
    unsigned int v6 = h32[s6 * 64 + lane];
    unsigned int v7 = h32[s7 * 64 + lane];
    float2 a0 = bfu(v0), a1 = bfu(v1), a2 = bfu(v2), a3 = bfu(v3);
    float2 a4 = bfu(v4), a5 = bfu(v5), a6 = bfu(v6), a7 = bfu(v7);
    acc.x += ((a0.x + a1.x) + (a2.x + a3.x)) + ((a4.x + a5.x) + (a6.x + a7.x));
    acc.y += ((a0.y + a1.y) + (a2.y + a3.y)) + ((a4.y + a5.y) + (a6.y + a7.y));
  }
  for (; j < end; ++j) {
    float2 a = bfu(h32[csr[j] * 64 + lane]);
    acc.x += a.x; acc.y += a.y;
  }
  ((unsigned int*)tout)[i * 64 + lane] =
      (unsigned int)f2bf(acc.x) | ((unsigned int)f2bf(acc.y) << 16);
}

// ---------------- fused MLP: hout = bf16(ReLU(t@W1+b1)@W2 + b2) ----------------
#define USTRIDE 136   // bf16 elems per LDS row: 272B = 16B aligned, ~2-way conflicts

__global__ __launch_bounds__(256) void k_mlp(const unsigned short* __restrict__ t,
                                             const unsigned short* __restrict__ w1t,
                                             const float* __restrict__ b1,
                                             const unsigned short* __restrict__ w2t,
                                             const float* __restrict__ b2,
                                             unsigned short* __restrict__ hout) {
  __shared__ unsigned short ulds[4][16 * USTRIDE];
  const int wid  = threadIdx.x >> 6;
  const int lane = threadIdx.x & 63;
  const int r16  = lane & 15;   // A row / B col / D col
  const int kg   = lane >> 4;   // k-group
  const int rowBase = blockIdx.x * 64 + wid * 16;

  f32x4 acc[8];
  #pragma unroll
  for (int nb = 0; nb < 8; ++nb) acc[nb] = (f32x4){0.f, 0.f, 0.f, 0.f};

  // GEMM1: u = t @ W1
  const int arow = rowBase + r16;
  const bool aval = arow < NN;
  #pragma unroll
  for (int s = 0; s < 4; ++s) {
    ABu au; au.v = (bf16x8)(__bf16)0.0f;
    if (aval) au.q = *(const uint4*)(t + arow * DD + s * 32 + kg * 8);
    #pragma unroll
    for (int nb = 0; nb < 8; ++nb) {
      ABu bu; bu.q = *(const uint4*)(w1t + (nb * 16 + r16) * DD + s * 32 + kg * 8);
      acc[nb] = __builtin_amdgcn_mfma_f32_16x16x32_bf16(au.v, bu.v, acc[nb], 0, 0, 0);
    }
  }

  // epilogue 1: bias + ReLU + bf16 -> per-wave LDS (transpose)
  unsigned short* myu = ulds[wid];
  #pragma unroll
  for (int nb = 0; nb < 8; ++nb) {
    int n = nb * 16 + r16;
    float bias = b1[n];
    #pragma unroll
    for (int reg = 0; reg < 4; ++reg) {
      int urow = kg * 4 + reg;
      float v = acc[nb][reg] + bias;
      v = v > 0.f ? v : 0.f;
      myu[urow * USTRIDE + n] = f2bf(v);
    }
  }
  __syncthreads();

  // GEMM2: hout = u @ W2
  #pragma unroll
  for (int nb = 0; nb < 8; ++nb) acc[nb] = (f32x4){0.f, 0.f, 0.f, 0.f};
  #pragma unroll
  for (int s = 0; s < 4; ++s) {
    ABu au; au.q = *(const uint4*)(myu + r16 * USTRIDE + s * 32 + kg * 8);
    #pragma unroll
    for (int nb = 0; nb < 8; ++nb) {
      ABu bu; bu.q = *(const uint4*)(w2t + (nb * 16 + r16) * DD + s * 32 + kg * 8);
      acc[nb] = __builtin_amdgcn_mfma_f32_16x16x32_bf16(au.v, bu.v, acc[nb], 0, 0, 0);
    }
  }

  // epilogue 2: bias + store bf16
  #pragma unroll
  for (int reg = 0; reg < 4; ++reg) {
    int row = rowBase + kg * 4 + reg;
    if (row < NN) {
      #pragma unroll
      for (int nb = 0; nb < 8; ++nb) {
        int n = nb * 16 + r16;
        hout[row * DD + n] = f2bf(acc[nb][reg] + b2[n]);
      }
    }
  }
}

// ---------------- pooling (batch is sorted) ----------------
__global__ void k_poolsum(const unsigned short* __restrict__ hb,
                          const int* __restrict__ batch,
                          float* __restrict__ sums) {
  const int t = threadIdx.x;  // 64: thread t owns feats 2t, 2t+1
  const unsigned int* h32 = (const unsigned int*)hb;
  int start = blockIdx.x * 256;
  int end = min(start + 256, NN);
  float2 acc = {0.f, 0.f};
  int cur = batch[start];
  for (int i = start; i < end; ++i) {
    int b = batch[i];
    if (b != cur) {
      atomicAdd(&sums[cur * DD + 2 * t], acc.x);
      atomicAdd(&sums[cur * DD + 2 * t + 1], acc.y);
      acc.x = 0.f; acc.y = 0.f; cur = b;
    }
    float2 v = bfu(h32[i * 64 + t]);
    acc.x += v.x; acc.y += v.y;
  }
  atomicAdd(&sums[cur * DD + 2 * t], acc.x);
  atomicAdd(&sums[cur * DD + 2 * t + 1], acc.y);
}

// counts via binary search on the SORTED batch array — no atomics.
__global__ void k_bounds(const int* __restrict__ batch, int* __restrict__ cnt) {
  int g = threadIdx.x;  // 128 threads, one block
  int lo = 0, hi = NN;
  while (lo < hi) { int mid = (lo + hi) >> 1; if (batch[mid] < g) lo = mid + 1; else hi = mid; }
  int s = lo;
  hi = NN;
  while (lo < hi) { int mid = (lo + hi) >> 1; if (batch[mid] < g + 1) lo = mid + 1; else hi = mid; }
  cnt[g] = lo - s;
}

__global__ void k_finalize(const float* __restrict__ sums, const int* __restrict__ cnt,
                           float* __restrict__ out) {
  int g = blockIdx.x, f = threadIdx.x;
  float c = (float)max(cnt[g], 1);
  out[g * DD + f] = sums[g * DD + f] / c;
}

// ---------------- launch ----------------
extern "C" void kernel_launch(void* const* d_in, const int* in_sizes, int n_in,
                              void* d_out, int out_size, void* d_ws, size_t ws_size,
                              hipStream_t stream) {
  const float* x    = (const float*)d_in[0];
  const int* ei     = (const int*)d_in[1];
  const int* src    = ei;
  const int* dst    = ei + NE;
  const int* batch  = (const int*)d_in[2];

  char* ws = (char*)d_ws;
  size_t off = 0;
  auto alloc = [&](size_t bytes) { char* p = ws + off; off = (off + bytes + 255) & ~(size_t)255; return p; };

  int*  deg    = (int*)alloc(2 * NN * 4);       // deg + cursor contiguous
  int*  cursor = deg + NN;
  int*  rowptr = (int*)alloc((NN + 1) * 4);
  int*  csr    = (int*)alloc(NE * 4);
  unsigned short* wt = (unsigned short*)alloc(6 * 16384 * 2);
  unsigned short* xb = (unsigned short*)alloc((size_t)NN * DD * 2);
  unsigned short* t  = (unsigned short*)alloc((size_t)NN * DD * 2);
  unsigned short* hA = (unsigned short*)alloc((size_t)NN * DD * 2);
  unsigned short* hB = (unsigned short*)alloc((size_t)NN * DD * 2);
  float* sums  = (float*)alloc(NG * DD * 4 + NG * 4);   // sums + cnt contiguous
  int*   cnt   = (int*)(sums + NG * DD);

  hipMemsetAsync(deg, 0, 2 * NN * 4, stream);
  hipMemsetAsync(sums, 0, NG * DD * 4 + NG * 4, stream);

  k_wconv<<<(6 * 16384 + 255) / 256, 256, 0, stream>>>(
      (const float*)d_in[3], (const float*)d_in[5],
      (const float*)d_in[7], (const float*)d_in[9],
      (const float*)d_in[11], (const float*)d_in[13], wt);
  k_xconv<<<(NN * DD / 4 + 255) / 256, 256, 0, stream>>>(x, xb);

  const int echunks = (NE + 255) / 256;
  k_count<<<8 * echunks, 256, 0, stream>>>(dst, deg);
  k_scan<<<1, 1024, 0, stream>>>(deg, rowptr);
  k_fill<<<8 * echunks, 256, 0, stream>>>(src, dst, rowptr, cursor, csr);

  const unsigned short* hin = xb;
  unsigned short* houts[3] = {hA, hB, hA};
  for (int l = 0; l < 3; ++l) {
    k_aggregate<<<(NN + 3) / 4, 256, 0, stream>>>(hin, rowptr, csr, t);
    k_mlp<<<(NN + 63) / 64, 256, 0, stream>>>(
        t, wt + (2 * l) * 16384, (const float*)d_in[4 + 4 * l],
        wt + (2 * l + 1) * 16384, (const float*)d_in[6 + 4 * l], houts[l]);
    hin = houts[l];
  }

  k_poolsum<<<(NN + 255) / 256, 64, 0, stream>>>(hin, batch, sums);
  k_bounds<<<1, 128, 0, stream>>>(batch, cnt);
  k_finalize<<<NG, 128, 0, stream>>>(sums, cnt, (float*)d_out);
}

// Round 8
// 744.458 us; speedup vs baseline: 1.8573x; 1.0672x over previous
//
#include <hip/hip_runtime.h>
#include <stdint.h>

#define NN 100000
#define NE 1600000
#define DD 128
#define NG 128
#define NPX 12500   // nodes per XCD partition (8 * 12500 = 100000)

using f32x4  = __attribute__((ext_vector_type(4))) float;
using bf16x8 = __attribute__((ext_vector_type(8))) __bf16;

__device__ __forceinline__ unsigned short f2bf(float f) {
  unsigned int u = __builtin_bit_cast(unsigned int, f);
  u = (u + 0x7FFFu + ((u >> 16) & 1u)) >> 16;
  return (unsigned short)u;
}

__device__ __forceinline__ float2 bfu(unsigned int u) {
  float2 r;
  r.x = __builtin_bit_cast(float, u << 16);
  r.y = __builtin_bit_cast(float, u & 0xffff0000u);
  return r;
}

union ABu { uint4 q; bf16x8 v; };

// ---------------- CSR build (XCD-partitioned scatter) ----------------
// blocks with bid&7==k handle only dst in [k*NPX,(k+1)*NPX): deg/cursor/csr
// lines stay resident+dirty in exactly one XCD's L2 -> no cross-XCD thrash.
__global__ void k_count(const int* __restrict__ dst, int* __restrict__ deg) {
  int xcd = blockIdx.x & 7;
  int e = (blockIdx.x >> 3) * 256 + threadIdx.x;
  if (e >= NE) return;
  int d = dst[e];
  if ((unsigned)(d - xcd * NPX) < (unsigned)NPX) atomicAdd(&deg[d], 1);
}

__global__ __launch_bounds__(1024) void k_scan(const int* __restrict__ deg,
                                               int* __restrict__ rowptr) {
  __shared__ int wsum[16];
  const int tid = threadIdx.x, wid = tid >> 6, lane = tid & 63;
  int carry = 0;
  for (int base = 0; base <= NN; base += 4096) {
    int idx = base + tid * 4;
    int v0 = (idx + 0 < NN) ? deg[idx + 0] : 0;
    int v1 = (idx + 1 < NN) ? deg[idx + 1] : 0;
    int v2 = (idx + 2 < NN) ? deg[idx + 2] : 0;
    int v3 = (idx + 3 < NN) ? deg[idx + 3] : 0;
    int tsum = v0 + v1 + v2 + v3;
    // inclusive wave scan
    int sc = tsum;
    #pragma unroll
    for (int off = 1; off < 64; off <<= 1) {
      int n = __shfl_up(sc, off);
      if (lane >= off) sc += n;
    }
    if (lane == 63) wsum[wid] = sc;
    __syncthreads();
    if (wid == 0 && lane < 16) {
      int w = wsum[lane];
      #pragma unroll
      for (int off = 1; off < 16; off <<= 1) {
        int n = __shfl_up(w, off);
        if (lane >= off) w += n;
      }
      wsum[lane] = w;
    }
    __syncthreads();
    int woff = (wid ? wsum[wid - 1] : 0) + carry;
    int total = wsum[15];
    int excl = woff + sc - tsum;
    if (idx     <= NN) rowptr[idx]     = excl;
    if (idx + 1 <= NN) rowptr[idx + 1] = excl + v0;
    if (idx + 2 <= NN) rowptr[idx + 2] = excl + v0 + v1;
    if (idx + 3 <= NN) rowptr[idx + 3] = excl + v0 + v1 + v2;
    __syncthreads();   // wsum reused next iteration
    carry += total;
  }
}

__global__ void k_fill(const int* __restrict__ src, const int* __restrict__ dst,
                       const int* __restrict__ rowptr, int* __restrict__ cursor,
                       int* __restrict__ csr) {
  int xcd = blockIdx.x & 7;
  int e = (blockIdx.x >> 3) * 256 + threadIdx.x;
  if (e >= NE) return;
  int d = dst[e];
  if ((unsigned)(d - xcd * NPX) < (unsigned)NPX) {
    int pos = rowptr[d] + atomicAdd(&cursor[d], 1);
    csr[pos] = src[e];
  }
}

// ---------------- weight transpose + bf16 convert ----------------
__global__ void k_wconv(const float* __restrict__ w0, const float* __restrict__ w1,
                        const float* __restrict__ w2, const float* __restrict__ w3,
                        const float* __restrict__ w4, const float* __restrict__ w5,
                        unsigned short* __restrict__ wt) {
  int idx = blockIdx.x * 256 + threadIdx.x;
  if (idx >= 6 * 16384) return;
  int m = idx >> 14, rem = idx & 16383;
  int n = rem >> 7, k = rem & 127;
  const float* W = (m == 0) ? w0 : (m == 1) ? w1 : (m == 2) ? w2
                 : (m == 3) ? w3 : (m == 4) ? w4 : w5;
  wt[idx] = f2bf(W[k * 128 + n]);   // wt[m][n][k] = W[k][n]
}

// ---------------- x -> bf16 ----------------
__global__ void k_xconv(const float* __restrict__ x, unsigned short* __restrict__ xb) {
  int i = blockIdx.x * 256 + threadIdx.x;   // one float4 per thread
  if (i >= NN * DD / 4) return;
  float4 v = ((const float4*)x)[i];
  uint2 p;
  p.x = (unsigned int)f2bf(v.x) | ((unsigned int)f2bf(v.y) << 16);
  p.y = (unsigned int)f2bf(v.z) | ((unsigned int)f2bf(v.w) << 16);
  ((uint2*)xb)[i] = p;
}

// ---------------- aggregation: t[i] = bf16(h[i] + sum_{j->i} h[src]) ----------------
__global__ void k_aggregate(const unsigned short* __restrict__ hb,
                            const int* __restrict__ rowptr,
                            const int* __restrict__ csr,
                            unsigned short* __restrict__ tout) {
  const int wid  = threadIdx.x >> 6;
  const int lane = threadIdx.x & 63;
  const int i = blockIdx.x * 4 + wid;
  if (i >= NN) return;
  const unsigned int* h32 = (const unsigned int*)hb;
  float2 acc = bfu(h32[i * 64 + lane]);
  const int beg = rowptr[i], end = rowptr[i + 1];
  int j = beg;
  for (; j + 7 < end; j += 8) {
    int s0 = csr[j],     s1 = csr[j + 1], s2 = csr[j + 2], s3 = csr[j + 3];
    int s4 = csr[j + 4], s5 = csr[j + 5], s6 = csr[j + 6], s7 = csr[j + 7];
    unsigned int v0 = h32[s0 * 64 + lane];
    unsigned int v1 = h32[s1 * 64 + lane];
    unsigned int v2 = h32[s2 * 64 + lane];
    unsigned int v3 = h32[s3 * 64 + lane];
    unsigned int v4 = h32[s4 * 64 + lane];
    unsigned int v5 = h32[s5 * 64 + lane];
    unsigned int v6 = h32[s6 * 64 + lane];
    unsigned int v7 = h32[s7 * 64 + lane];
    float2 a0 = bfu(v0), a1 = bfu(v1), a2 = bfu(v2), a3 = bfu(v3);
    float2 a4 = bfu(v4), a5 = bfu(v5), a6 = bfu(v6), a7 = bfu(v7);
    acc.x += ((a0.x + a1.x) + (a2.x + a3.x)) + ((a4.x + a5.x) + (a6.x + a7.x));
    acc.y += ((a0.y + a1.y) + (a2.y + a3.y)) + ((a4.y + a5.y) + (a6.y + a7.y));
  }
  for (; j < end; ++j) {
    float2 a = bfu(h32[csr[j] * 64 + lane]);
    acc.x += a.x; acc.y += a.y;
  }
  ((unsigned int*)tout)[i * 64 + lane] =
      (unsigned int)f2bf(acc.x) | ((unsigned int)f2bf(acc.y) << 16);
}

// ---------------- fused MLP: hout = bf16(ReLU(t@W1+b1)@W2 + b2) ----------------
#define USTRIDE 136   // bf16 elems per LDS row: 272B = 16B aligned, ~2-way conflicts

__global__ __launch_bounds__(256) void k_mlp(const unsigned short* __restrict__ t,
                                             const unsigned short* __restrict__ w1t,
                                             const float* __restrict__ b1,
                                             const unsigned short* __restrict__ w2t,
                                             const float* __restrict__ b2,
                                             unsigned short* __restrict__ hout) {
  __shared__ unsigned short ulds[4][16 * USTRIDE];
  const int wid  = threadIdx.x >> 6;
  const int lane = threadIdx.x & 63;
  const int r16  = lane & 15;   // A row / B col / D col
  const int kg   = lane >> 4;   // k-group
  const int rowBase = blockIdx.x * 64 + wid * 16;

  f32x4 acc[8];
  #pragma unroll
  for (int nb = 0; nb < 8; ++nb) acc[nb] = (f32x4){0.f, 0.f, 0.f, 0.f};

  // GEMM1: u = t @ W1
  const int arow = rowBase + r16;
  const bool aval = arow < NN;
  #pragma unroll
  for (int s = 0; s < 4; ++s) {
    ABu au; au.v = (bf16x8)(__bf16)0.0f;
    if (aval) au.q = *(const uint4*)(t + arow * DD + s * 32 + kg * 8);
    #pragma unroll
    for (int nb = 0; nb < 8; ++nb) {
      ABu bu; bu.q = *(const uint4*)(w1t + (nb * 16 + r16) * DD + s * 32 + kg * 8);
      acc[nb] = __builtin_amdgcn_mfma_f32_16x16x32_bf16(au.v, bu.v, acc[nb], 0, 0, 0);
    }
  }

  // epilogue 1: bias + ReLU + bf16 -> per-wave LDS (transpose)
  unsigned short* myu = ulds[wid];
  #pragma unroll
  for (int nb = 0; nb < 8; ++nb) {
    int n = nb * 16 + r16;
    float bias = b1[n];
    #pragma unroll
    for (int reg = 0; reg < 4; ++reg) {
      int urow = kg * 4 + reg;
      float v = acc[nb][reg] + bias;
      v = v > 0.f ? v : 0.f;
      myu[urow * USTRIDE + n] = f2bf(v);
    }
  }
  __syncthreads();

  // GEMM2: hout = u @ W2
  #pragma unroll
  for (int nb = 0; nb < 8; ++nb) acc[nb] = (f32x4){0.f, 0.f, 0.f, 0.f};
  #pragma unroll
  for (int s = 0; s < 4; ++s) {
    ABu au; au.q = *(const uint4*)(myu + r16 * USTRIDE + s * 32 + kg * 8);
    #pragma unroll
    for (int nb = 0; nb < 8; ++nb) {
      ABu bu; bu.q = *(const uint4*)(w2t + (nb * 16 + r16) * DD + s * 32 + kg * 8);
      acc[nb] = __builtin_amdgcn_mfma_f32_16x16x32_bf16(au.v, bu.v, acc[nb], 0, 0, 0);
    }
  }

  // epilogue 2: bias + store bf16
  #pragma unroll
  for (int reg = 0; reg < 4; ++reg) {
    int row = rowBase + kg * 4 + reg;
    if (row < NN) {
      #pragma unroll
      for (int nb = 0; nb < 8; ++nb) {
        int n = nb * 16 + r16;
        hout[row * DD + n] = f2bf(acc[nb][reg] + b2[n]);
      }
    }
  }
}

// ---------------- fused pooling: one block per graph (batch sorted) ----------------
// binary-search segment bounds, branch-free 4-row-parallel streaming sum,
// LDS reduce, write mean directly. No atomics, no separate cnt/finalize.
__global__ __launch_bounds__(256) void k_pool(const unsigned short* __restrict__ hb,
                                              const int* __restrict__ batch,
                                              float* __restrict__ out) {
  const int g  = blockIdx.x;         // 128 blocks = 128 graphs
  const int f2 = threadIdx.x & 63;   // uint index (2 feats)
  const int rp = threadIdx.x >> 6;   // 0..3 row-parallel wave
  // bounds via binary search (redundant per-thread; L2-cached, lanes uniform)
  int lo = 0, hi = NN;
  while (lo < hi) { int m = (lo + hi) >> 1; if (batch[m] < g) lo = m + 1; else hi = m; }
  const int start = lo;
  hi = NN;
  while (lo < hi) { int m = (lo + hi) >> 1; if (batch[m] < g + 1) lo = m + 1; else hi = m; }
  const int end = lo;

  const unsigned int* h32 = (const unsigned int*)hb;
  float2 acc = {0.f, 0.f};
  int i = start + rp;
  // 2-deep manual unroll: two independent loads in flight per iteration
  for (; i + 4 < end; i += 8) {
    float2 a = bfu(h32[(size_t)i * 64 + f2]);
    float2 b = bfu(h32[(size_t)(i + 4) * 64 + f2]);
    acc.x += a.x + b.x; acc.y += a.y + b.y;
  }
  for (; i < end; i += 4) {
    float2 a = bfu(h32[(size_t)i * 64 + f2]);
    acc.x += a.x; acc.y += a.y;
  }

  __shared__ float2 part[4][64];
  part[rp][f2] = acc;
  __syncthreads();
  if (rp == 0) {
    float2 t0 = part[0][f2], t1 = part[1][f2], t2 = part[2][f2], t3 = part[3][f2];
    float inv = 1.0f / (float)max(end - start, 1);
    out[g * DD + 2 * f2]     = (t0.x + t1.x + t2.x + t3.x) * inv;
    out[g * DD + 2 * f2 + 1] = (t0.y + t1.y + t2.y + t3.y) * inv;
  }
}

// ---------------- launch ----------------
extern "C" void kernel_launch(void* const* d_in, const int* in_sizes, int n_in,
                              void* d_out, int out_size, void* d_ws, size_t ws_size,
                              hipStream_t stream) {
  const float* x    = (const float*)d_in[0];
  const int* ei     = (const int*)d_in[1];
  const int* src    = ei;
  const int* dst    = ei + NE;
  const int* batch  = (const int*)d_in[2];

  char* ws = (char*)d_ws;
  size_t off = 0;
  auto alloc = [&](size_t bytes) { char* p = ws + off; off = (off + bytes + 255) & ~(size_t)255; return p; };

  int*  deg    = (int*)alloc(2 * NN * 4);       // deg + cursor contiguous
  int*  cursor = deg + NN;
  int*  rowptr = (int*)alloc((NN + 1) * 4);
  int*  csr    = (int*)alloc(NE * 4);
  unsigned short* wt = (unsigned short*)alloc(6 * 16384 * 2);
  unsigned short* xb = (unsigned short*)alloc((size_t)NN * DD * 2);
  unsigned short* t  = (unsigned short*)alloc((size_t)NN * DD * 2);
  unsigned short* hA = (unsigned short*)alloc((size_t)NN * DD * 2);
  unsigned short* hB = (unsigned short*)alloc((size_t)NN * DD * 2);

  hipMemsetAsync(deg, 0, 2 * NN * 4, stream);

  k_wconv<<<(6 * 16384 + 255) / 256, 256, 0, stream>>>(
      (const float*)d_in[3], (const float*)d_in[5],
      (const float*)d_in[7], (const float*)d_in[9],
      (const float*)d_in[11], (const float*)d_in[13], wt);
  k_xconv<<<(NN * DD / 4 + 255) / 256, 256, 0, stream>>>(x, xb);

  const int echunks = (NE + 255) / 256;
  k_count<<<8 * echunks, 256, 0, stream>>>(dst, deg);
  k_scan<<<1, 1024, 0, stream>>>(deg, rowptr);
  k_fill<<<8 * echunks, 256, 0, stream>>>(src, dst, rowptr, cursor, csr);

  const unsigned short* hin = xb;
  unsigned short* houts[3] = {hA, hB, hA};
  for (int l = 0; l < 3; ++l) {
    k_aggregate<<<(NN + 3) / 4, 256, 0, stream>>>(hin, rowptr, csr, t);
    k_mlp<<<(NN + 63) / 64, 256, 0, stream>>>(
        t, wt + (2 * l) * 16384, (const float*)d_in[4 + 4 * l],
        wt + (2 * l + 1) * 16384, (const float*)d_in[6 + 4 * l], houts[l]);
    hin = houts[l];
  }

  k_pool<<<NG, 256, 0, stream>>>(hin, batch, (float*)d_out);
}

// Round 9
// 717.939 us; speedup vs baseline: 1.9259x; 1.0369x over previous
//
#include <hip/hip_runtime.h>
#include <stdint.h>

#define NN 100000
#define NE 1600000
#define DD 128
#define NG 128
#define NPX 12500   // nodes per XCD partition (8 * 12500 = 100000)

using f32x4  = __attribute__((ext_vector_type(4))) float;
using bf16x8 = __attribute__((ext_vector_type(8))) __bf16;

__device__ __forceinline__ unsigned short f2bf(float f) {
  unsigned int u = __builtin_bit_cast(unsigned int, f);
  u = (u + 0x7FFFu + ((u >> 16) & 1u)) >> 16;
  return (unsigned short)u;
}

__device__ __forceinline__ float2 bfu(unsigned int u) {
  float2 r;
  r.x = __builtin_bit_cast(float, u << 16);
  r.y = __builtin_bit_cast(float, u & 0xffff0000u);
  return r;
}

__device__ __forceinline__ void addu4(float* a, uint4 v) {
  float2 p0 = bfu(v.x), p1 = bfu(v.y), p2 = bfu(v.z), p3 = bfu(v.w);
  a[0] += p0.x; a[1] += p0.y; a[2] += p1.x; a[3] += p1.y;
  a[4] += p2.x; a[5] += p2.y; a[6] += p3.x; a[7] += p3.y;
}

union ABu { uint4 q; bf16x8 v; };

// ---------------- CSR build (XCD-partitioned scatter) ----------------
__global__ void k_count(const int* __restrict__ dst, int* __restrict__ deg) {
  int xcd = blockIdx.x & 7;
  int e = (blockIdx.x >> 3) * 256 + threadIdx.x;
  if (e >= NE) return;
  int d = dst[e];
  if ((unsigned)(d - xcd * NPX) < (unsigned)NPX) atomicAdd(&deg[d], 1);
}

__global__ __launch_bounds__(1024) void k_scan(const int* __restrict__ deg,
                                               int* __restrict__ rowptr) {
  __shared__ int wsum[16];
  const int tid = threadIdx.x, wid = tid >> 6, lane = tid & 63;
  int carry = 0;
  for (int base = 0; base <= NN; base += 4096) {
    int idx = base + tid * 4;
    int v0 = (idx + 0 < NN) ? deg[idx + 0] : 0;
    int v1 = (idx + 1 < NN) ? deg[idx + 1] : 0;
    int v2 = (idx + 2 < NN) ? deg[idx + 2] : 0;
    int v3 = (idx + 3 < NN) ? deg[idx + 3] : 0;
    int tsum = v0 + v1 + v2 + v3;
    int sc = tsum;
    #pragma unroll
    for (int off = 1; off < 64; off <<= 1) {
      int n = __shfl_up(sc, off);
      if (lane >= off) sc += n;
    }
    if (lane == 63) wsum[wid] = sc;
    __syncthreads();
    if (wid == 0 && lane < 16) {
      int w = wsum[lane];
      #pragma unroll
      for (int off = 1; off < 16; off <<= 1) {
        int n = __shfl_up(w, off);
        if (lane >= off) w += n;
      }
      wsum[lane] = w;
    }
    __syncthreads();
    int woff = (wid ? wsum[wid - 1] : 0) + carry;
    int total = wsum[15];
    int excl = woff + sc - tsum;
    if (idx     <= NN) rowptr[idx]     = excl;
    if (idx + 1 <= NN) rowptr[idx + 1] = excl + v0;
    if (idx + 2 <= NN) rowptr[idx + 2] = excl + v0 + v1;
    if (idx + 3 <= NN) rowptr[idx + 3] = excl + v0 + v1 + v2;
    __syncthreads();
    carry += total;
  }
}

__global__ void k_fill(const int* __restrict__ src, const int* __restrict__ dst,
                       const int* __restrict__ rowptr, int* __restrict__ cursor,
                       int* __restrict__ csr) {
  int xcd = blockIdx.x & 7;
  int e = (blockIdx.x >> 3) * 256 + threadIdx.x;
  if (e >= NE) return;
  int d = dst[e];
  if ((unsigned)(d - xcd * NPX) < (unsigned)NPX) {
    int pos = rowptr[d] + atomicAdd(&cursor[d], 1);
    csr[pos] = src[e];
  }
}

// ---------------- weight transpose + bf16 convert ----------------
__global__ void k_wconv(const float* __restrict__ w0, const float* __restrict__ w1,
                        const float* __restrict__ w2, const float* __restrict__ w3,
                        const float* __restrict__ w4, const float* __restrict__ w5,
                        unsigned short* __restrict__ wt) {
  int idx = blockIdx.x * 256 + threadIdx.x;
  if (idx >= 6 * 16384) return;
  int m = idx >> 14, rem = idx & 16383;
  int n = rem >> 7, k = rem & 127;
  const float* W = (m == 0) ? w0 : (m == 1) ? w1 : (m == 2) ? w2
                 : (m == 3) ? w3 : (m == 4) ? w4 : w5;
  wt[idx] = f2bf(W[k * 128 + n]);   // wt[m][n][k] = W[k][n]
}

// ---------------- x -> bf16 ----------------
__global__ void k_xconv(const float* __restrict__ x, unsigned short* __restrict__ xb) {
  int i = blockIdx.x * 256 + threadIdx.x;
  if (i >= NN * DD / 4) return;
  float4 v = ((const float4*)x)[i];
  uint2 p;
  p.x = (unsigned int)f2bf(v.x) | ((unsigned int)f2bf(v.y) << 16);
  p.y = (unsigned int)f2bf(v.z) | ((unsigned int)f2bf(v.w) << 16);
  ((uint2*)xb)[i] = p;
}

// ---------------- fused GIN layer: aggregate + MLP ----------------
// Block = 256 threads = 4 waves; each wave owns 16 nodes, fully independent
// (no barriers). Phase 1: 4 lane-groups of 16 gather whole 256B rows via
// dwordx4 (1KB/inst), accumulate fp32, round to bf16 into a wave-private
// XOR-swizzled LDS tile [16][128]. Phase 2: GEMM1 (A from LDS), epilogue
// overwrites same rows with u, GEMM2, bf16 store.
// Swizzle: 16B chunk index c of row r stored at c ^ (r & 7)  [m214 pattern].
__global__ __launch_bounds__(256) void k_gin(const unsigned short* __restrict__ hb,
                                             const int* __restrict__ rowptr,
                                             const int* __restrict__ csr,
                                             const unsigned short* __restrict__ w1t,
                                             const float* __restrict__ b1,
                                             const unsigned short* __restrict__ w2t,
                                             const float* __restrict__ b2,
                                             unsigned short* __restrict__ hout) {
  __shared__ unsigned short tl[64 * DD];   // 16 KB
  const int wid  = threadIdx.x >> 6;
  const int lane = threadIdx.x & 63;
  const int r16  = lane & 15;
  const int kg   = lane >> 4;
  const int waveBase = blockIdx.x * 64 + wid * 16;
  unsigned short* wt_ = tl + (wid * 16) * DD;   // wave-private 16-row tile
  const uint4* h4 = (const uint4*)hb;

  // ---- phase 1: aggregate 16 nodes (4 groups x 4 node-iterations) ----
  #pragma unroll
  for (int it = 0; it < 4; ++it) {
    const int lrow = it * 4 + kg;          // local row 0..15
    const int node = waveBase + lrow;
    float acc[8] = {0.f,0.f,0.f,0.f,0.f,0.f,0.f,0.f};
    if (node < NN) {
      addu4(acc, h4[(size_t)node * 16 + r16]);   // self term
      int j = rowptr[node];
      const int je = rowptr[node + 1];
      for (; j + 1 < je; j += 2) {
        int s0 = csr[j], s1 = csr[j + 1];
        uint4 v0 = h4[(size_t)s0 * 16 + r16];
        uint4 v1 = h4[(size_t)s1 * 16 + r16];
        addu4(acc, v0); addu4(acc, v1);
      }
      if (j < je) addu4(acc, h4[(size_t)csr[j] * 16 + r16]);
    }
    uint4 p;
    p.x = (unsigned int)f2bf(acc[0]) | ((unsigned int)f2bf(acc[1]) << 16);
    p.y = (unsigned int)f2bf(acc[2]) | ((unsigned int)f2bf(acc[3]) << 16);
    p.z = (unsigned int)f2bf(acc[4]) | ((unsigned int)f2bf(acc[5]) << 16);
    p.w = (unsigned int)f2bf(acc[6]) | ((unsigned int)f2bf(acc[7]) << 16);
    *(uint4*)(wt_ + lrow * DD + ((r16 ^ (lrow & 7)) << 3)) = p;
  }
  // no barrier: tile is wave-private

  // ---- phase 2a: GEMM1  u = ReLU(t @ W1 + b1) ----
  f32x4 acc[8];
  #pragma unroll
  for (int nb = 0; nb < 8; ++nb) acc[nb] = (f32x4){0.f, 0.f, 0.f, 0.f};
  #pragma unroll
  for (int s = 0; s < 4; ++s) {
    ABu au;
    au.q = *(const uint4*)(wt_ + r16 * DD + ((((s << 2) + kg) ^ (r16 & 7)) << 3));
    #pragma unroll
    for (int nb = 0; nb < 8; ++nb) {
      ABu bu; bu.q = *(const uint4*)(w1t + (nb * 16 + r16) * DD + s * 32 + kg * 8);
      acc[nb] = __builtin_amdgcn_mfma_f32_16x16x32_bf16(au.v, bu.v, acc[nb], 0, 0, 0);
    }
  }
  // epilogue 1: bias + ReLU + bf16 -> overwrite own LDS rows (u tile)
  #pragma unroll
  for (int nb = 0; nb < 8; ++nb) {
    int n = nb * 16 + r16;
    float bias = b1[n];
    #pragma unroll
    for (int reg = 0; reg < 4; ++reg) {
      int urow = (kg << 2) + reg;
      float v = acc[nb][reg] + bias;
      v = v > 0.f ? v : 0.f;
      wt_[urow * DD + ((((n >> 3) ^ (urow & 7)) << 3) | (n & 7))] = f2bf(v);
    }
  }

  // ---- phase 2b: GEMM2  hout = u @ W2 + b2 ----
  #pragma unroll
  for (int nb = 0; nb < 8; ++nb) acc[nb] = (f32x4){0.f, 0.f, 0.f, 0.f};
  #pragma unroll
  for (int s = 0; s < 4; ++s) {
    ABu au;
    au.q = *(const uint4*)(wt_ + r16 * DD + ((((s << 2) + kg) ^ (r16 & 7)) << 3));
    #pragma unroll
    for (int nb = 0; nb < 8; ++nb) {
      ABu bu; bu.q = *(const uint4*)(w2t + (nb * 16 + r16) * DD + s * 32 + kg * 8);
      acc[nb] = __builtin_amdgcn_mfma_f32_16x16x32_bf16(au.v, bu.v, acc[nb], 0, 0, 0);
    }
  }
  #pragma unroll
  for (int reg = 0; reg < 4; ++reg) {
    int row = waveBase + (kg << 2) + reg;
    if (row < NN) {
      #pragma unroll
      for (int nb = 0; nb < 8; ++nb) {
        int n = nb * 16 + r16;
        hout[row * DD + n] = f2bf(acc[nb][reg] + b2[n]);
      }
    }
  }
}

// ---------------- fused pooling: one block per graph (batch sorted) ----------------
__global__ __launch_bounds__(256) void k_pool(const unsigned short* __restrict__ hb,
                                              const int* __restrict__ batch,
                                              float* __restrict__ out) {
  const int g  = blockIdx.x;
  const int f2 = threadIdx.x & 63;
  const int rp = threadIdx.x >> 6;
  int lo = 0, hi = NN;
  while (lo < hi) { int m = (lo + hi) >> 1; if (batch[m] < g) lo = m + 1; else hi = m; }
  const int start = lo;
  hi = NN;
  while (lo < hi) { int m = (lo + hi) >> 1; if (batch[m] < g + 1) lo = m + 1; else hi = m; }
  const int end = lo;

  const unsigned int* h32 = (const unsigned int*)hb;
  float2 acc = {0.f, 0.f};
  int i = start + rp;
  for (; i + 4 < end; i += 8) {
    float2 a = bfu(h32[(size_t)i * 64 + f2]);
    float2 b = bfu(h32[(size_t)(i + 4) * 64 + f2]);
    acc.x += a.x + b.x; acc.y += a.y + b.y;
  }
  for (; i < end; i += 4) {
    float2 a = bfu(h32[(size_t)i * 64 + f2]);
    acc.x += a.x; acc.y += a.y;
  }

  __shared__ float2 part[4][64];
  part[rp][f2] = acc;
  __syncthreads();
  if (rp == 0) {
    float2 t0 = part[0][f2], t1 = part[1][f2], t2 = part[2][f2], t3 = part[3][f2];
    float inv = 1.0f / (float)max(end - start, 1);
    out[g * DD + 2 * f2]     = (t0.x + t1.x + t2.x + t3.x) * inv;
    out[g * DD + 2 * f2 + 1] = (t0.y + t1.y + t2.y + t3.y) * inv;
  }
}

// ---------------- launch ----------------
extern "C" void kernel_launch(void* const* d_in, const int* in_sizes, int n_in,
                              void* d_out, int out_size, void* d_ws, size_t ws_size,
                              hipStream_t stream) {
  const float* x    = (const float*)d_in[0];
  const int* ei     = (const int*)d_in[1];
  const int* src    = ei;
  const int* dst    = ei + NE;
  const int* batch  = (const int*)d_in[2];

  char* ws = (char*)d_ws;
  size_t off = 0;
  auto alloc = [&](size_t bytes) { char* p = ws + off; off = (off + bytes + 255) & ~(size_t)255; return p; };

  int*  deg    = (int*)alloc(2 * NN * 4);       // deg + cursor contiguous
  int*  cursor = deg + NN;
  int*  rowptr = (int*)alloc((NN + 1) * 4);
  int*  csr    = (int*)alloc(NE * 4);
  unsigned short* wt = (unsigned short*)alloc(6 * 16384 * 2);
  unsigned short* xb = (unsigned short*)alloc((size_t)NN * DD * 2);
  unsigned short* hA = (unsigned short*)alloc((size_t)NN * DD * 2);
  unsigned short* hB = (unsigned short*)alloc((size_t)NN * DD * 2);

  hipMemsetAsync(deg, 0, 2 * NN * 4, stream);

  k_wconv<<<(6 * 16384 + 255) / 256, 256, 0, stream>>>(
      (const float*)d_in[3], (const float*)d_in[5],
      (const float*)d_in[7], (const float*)d_in[9],
      (const float*)d_in[11], (const float*)d_in[13], wt);
  k_xconv<<<(NN * DD / 4 + 255) / 256, 256, 0, stream>>>(x, xb);

  const int echunks = (NE + 255) / 256;
  k_count<<<8 * echunks, 256, 0, stream>>>(dst, deg);
  k_scan<<<1, 1024, 0, stream>>>(deg, rowptr);
  k_fill<<<8 * echunks, 256, 0, stream>>>(src, dst, rowptr, cursor, csr);

  const unsigned short* hin = xb;
  unsigned short* houts[3] = {hA, hB, hA};
  for (int l = 0; l < 3; ++l) {
    k_gin<<<(NN + 63) / 64, 256, 0, stream>>>(
        hin, rowptr, csr,
        wt + (2 * l) * 16384, (const float*)d_in[4 + 4 * l],
        wt + (2 * l + 1) * 16384, (const float*)d_in[6 + 4 * l], houts[l]);
    hin = houts[l];
  }

  k_pool<<<NG, 256, 0, stream>>>(hin, batch, (float*)d_out);
}

// Round 10
// 625.086 us; speedup vs baseline: 2.2119x; 1.1485x over previous
//
#include <hip/hip_runtime.h>
#include <stdint.h>

#define NN 100000
#define NE 1600000
#define DD 128
#define NG 128
#define NPX 12500     // nodes per XCD partition (8 * 12500 = 100000)
#define NBS 25        // scan blocks: 25 * 4096 > NN+1

using f32x4  = __attribute__((ext_vector_type(4))) float;
using bf16x8 = __attribute__((ext_vector_type(8))) __bf16;

__device__ __forceinline__ unsigned short f2bf(float f) {
  unsigned int u = __builtin_bit_cast(unsigned int, f);
  u = (u + 0x7FFFu + ((u >> 16) & 1u)) >> 16;
  return (unsigned short)u;
}

__device__ __forceinline__ float2 bfu(unsigned int u) {
  float2 r;
  r.x = __builtin_bit_cast(float, u << 16);
  r.y = __builtin_bit_cast(float, u & 0xffff0000u);
  return r;
}

__device__ __forceinline__ void addu4(float* a, uint4 v) {
  float2 p0 = bfu(v.x), p1 = bfu(v.y), p2 = bfu(v.z), p3 = bfu(v.w);
  a[0] += p0.x; a[1] += p0.y; a[2] += p1.x; a[3] += p1.y;
  a[4] += p2.x; a[5] += p2.y; a[6] += p3.x; a[7] += p3.y;
}

union ABu { uint4 q; bf16x8 v; };

// ---------------- CSR build (XCD-partitioned scatter) ----------------
__global__ void k_count(const int* __restrict__ dst, int* __restrict__ deg) {
  int xcd = blockIdx.x & 7;
  int e = (blockIdx.x >> 3) * 256 + threadIdx.x;
  if (e >= NE) return;
  int d = dst[e];
  if ((unsigned)(d - xcd * NPX) < (unsigned)NPX) atomicAdd(&deg[d], 1);
}

// ---- 3-kernel scan: rowptr = exclusive_scan(deg), rowptr[NN] = total ----
__global__ __launch_bounds__(1024) void k_scanA(const int* __restrict__ deg,
                                                int* __restrict__ rowptr,
                                                int* __restrict__ bsum) {
  __shared__ int wsum[16];
  const int tid = threadIdx.x, wid = tid >> 6, lane = tid & 63;
  int idx = blockIdx.x * 4096 + tid * 4;
  int v0 = (idx + 0 < NN) ? deg[idx + 0] : 0;
  int v1 = (idx + 1 < NN) ? deg[idx + 1] : 0;
  int v2 = (idx + 2 < NN) ? deg[idx + 2] : 0;
  int v3 = (idx + 3 < NN) ? deg[idx + 3] : 0;
  int tsum = v0 + v1 + v2 + v3;
  int sc = tsum;
  #pragma unroll
  for (int off = 1; off < 64; off <<= 1) {
    int n = __shfl_up(sc, off);
    if (lane >= off) sc += n;
  }
  if (lane == 63) wsum[wid] = sc;
  __syncthreads();
  if (wid == 0 && lane < 16) {
    int w = wsum[lane];
    #pragma unroll
    for (int off = 1; off < 16; off <<= 1) {
      int n = __shfl_up(w, off);
      if (lane >= off) w += n;
    }
    wsum[lane] = w;
  }
  __syncthreads();
  int excl = (wid ? wsum[wid - 1] : 0) + sc - tsum;
  if (idx     <= NN) rowptr[idx]     = excl;
  if (idx + 1 <= NN) rowptr[idx + 1] = excl + v0;
  if (idx + 2 <= NN) rowptr[idx + 2] = excl + v0 + v1;
  if (idx + 3 <= NN) rowptr[idx + 3] = excl + v0 + v1 + v2;
  if (tid == 0) bsum[blockIdx.x] = 0;          // init for scanB read
  if (tid == 1023) bsum[blockIdx.x] = wsum[15]; // block total (wsum[15] = block sum)
}

__global__ void k_scanB(int* __restrict__ bsum) {
  int lane = threadIdx.x & 63;
  int v = (lane < NBS) ? bsum[lane] : 0;
  int sc = v;
  #pragma unroll
  for (int off = 1; off < 64; off <<= 1) {
    int n = __shfl_up(sc, off);
    if (lane >= off) sc += n;
  }
  if (lane < NBS) bsum[lane] = sc - v;   // exclusive
}

__global__ __launch_bounds__(1024) void k_scanC(int* __restrict__ rowptr,
                                                const int* __restrict__ bsum) {
  int add = bsum[blockIdx.x];
  int idx = blockIdx.x * 4096 + threadIdx.x * 4;
  if (idx     <= NN) rowptr[idx]     += add;
  if (idx + 1 <= NN) rowptr[idx + 1] += add;
  if (idx + 2 <= NN) rowptr[idx + 2] += add;
  if (idx + 3 <= NN) rowptr[idx + 3] += add;
}

__global__ void k_fill(const int* __restrict__ src, const int* __restrict__ dst,
                       const int* __restrict__ rowptr, int* __restrict__ cursor,
                       int* __restrict__ csr) {
  int xcd = blockIdx.x & 7;
  int e = (blockIdx.x >> 3) * 256 + threadIdx.x;
  if (e >= NE) return;
  int d = dst[e];
  if ((unsigned)(d - xcd * NPX) < (unsigned)NPX) {
    int pos = rowptr[d] + atomicAdd(&cursor[d], 1);
    csr[pos] = src[e];
  }
}

// ---------------- weight transpose + bf16 convert ----------------
__global__ void k_wconv(const float* __restrict__ w0, const float* __restrict__ w1,
                        const float* __restrict__ w2, const float* __restrict__ w3,
                        const float* __restrict__ w4, const float* __restrict__ w5,
                        unsigned short* __restrict__ wt) {
  int idx = blockIdx.x * 256 + threadIdx.x;
  if (idx >= 6 * 16384) return;
  int m = idx >> 14, rem = idx & 16383;
  int n = rem >> 7, k = rem & 127;
  const float* W = (m == 0) ? w0 : (m == 1) ? w1 : (m == 2) ? w2
                 : (m == 3) ? w3 : (m == 4) ? w4 : w5;
  wt[idx] = f2bf(W[k * 128 + n]);   // wt[m][n][k] = W[k][n]
}

// ---------------- x -> bf16 ----------------
__global__ void k_xconv(const float* __restrict__ x, unsigned short* __restrict__ xb) {
  int i = blockIdx.x * 256 + threadIdx.x;
  if (i >= NN * DD / 4) return;
  float4 v = ((const float4*)x)[i];
  uint2 p;
  p.x = (unsigned int)f2bf(v.x) | ((unsigned int)f2bf(v.y) << 16);
  p.y = (unsigned int)f2bf(v.z) | ((unsigned int)f2bf(v.w) << 16);
  ((uint2*)xb)[i] = p;
}

// ---------------- fused GIN layer: aggregate + MLP (1 wave / 16 nodes) ----------------
// 6250 blocks x 64 threads. Phase 1: lane-group kg gathers row lrow=it*4+kg;
// 4 rows in flight per lane (batched idx loads -> batched dwordx4 row loads);
// fp32 accumulate; bf16 -> XOR-swizzled LDS tile [16][128] (chunk c ^= row&7).
// Phase 2: GEMM1 from LDS, epilogue overwrites tile with u, GEMM2, store.
__global__ __launch_bounds__(64) void k_gin(const unsigned short* __restrict__ hb,
                                            const int* __restrict__ rowptr,
                                            const int* __restrict__ csr,
                                            const unsigned short* __restrict__ w1t,
                                            const float* __restrict__ b1,
                                            const unsigned short* __restrict__ w2t,
                                            const float* __restrict__ b2,
                                            unsigned short* __restrict__ hout) {
  __shared__ unsigned short wt_[16 * DD];   // 4 KB, wave-private
  const int lane = threadIdx.x;
  const int r16  = lane & 15;
  const int kg   = lane >> 4;
  const int waveBase = blockIdx.x * 16;
  const uint4* h4 = (const uint4*)hb;

  // ---- phase 1: aggregate ----
  #pragma unroll
  for (int it = 0; it < 4; ++it) {
    const int lrow = it * 4 + kg;
    const int node = waveBase + lrow;
    float acc[8] = {0.f,0.f,0.f,0.f,0.f,0.f,0.f,0.f};
    if (node < NN) {
      addu4(acc, h4[(size_t)node * 16 + r16]);   // self
      int j = rowptr[node];
      const int je = rowptr[node + 1];
      for (; j + 3 < je; j += 4) {
        int s0 = csr[j], s1 = csr[j + 1], s2 = csr[j + 2], s3 = csr[j + 3];
        uint4 v0 = h4[(size_t)s0 * 16 + r16];
        uint4 v1 = h4[(size_t)s1 * 16 + r16];
        uint4 v2 = h4[(size_t)s2 * 16 + r16];
        uint4 v3 = h4[(size_t)s3 * 16 + r16];
        addu4(acc, v0); addu4(acc, v1); addu4(acc, v2); addu4(acc, v3);
      }
      for (; j < je; ++j) addu4(acc, h4[(size_t)csr[j] * 16 + r16]);
    }
    uint4 p;
    p.x = (unsigned int)f2bf(acc[0]) | ((unsigned int)f2bf(acc[1]) << 16);
    p.y = (unsigned int)f2bf(acc[2]) | ((unsigned int)f2bf(acc[3]) << 16);
    p.z = (unsigned int)f2bf(acc[4]) | ((unsigned int)f2bf(acc[5]) << 16);
    p.w = (unsigned int)f2bf(acc[6]) | ((unsigned int)f2bf(acc[7]) << 16);
    *(uint4*)(wt_ + lrow * DD + ((r16 ^ (lrow & 7)) << 3)) = p;
  }
  // wave-private tile: no barrier needed

  // ---- phase 2a: GEMM1  u = ReLU(t @ W1 + b1) ----
  f32x4 acc[8];
  #pragma unroll
  for (int nb = 0; nb < 8; ++nb) acc[nb] = (f32x4){0.f, 0.f, 0.f, 0.f};
  #pragma unroll
  for (int s = 0; s < 4; ++s) {
    ABu au;
    au.q = *(const uint4*)(wt_ + r16 * DD + ((((s << 2) + kg) ^ (r16 & 7)) << 3));
    #pragma unroll
    for (int nb = 0; nb < 8; ++nb) {
      ABu bu; bu.q = *(const uint4*)(w1t + (nb * 16 + r16) * DD + s * 32 + kg * 8);
      acc[nb] = __builtin_amdgcn_mfma_f32_16x16x32_bf16(au.v, bu.v, acc[nb], 0, 0, 0);
    }
  }
  #pragma unroll
  for (int nb = 0; nb < 8; ++nb) {
    int n = nb * 16 + r16;
    float bias = b1[n];
    #pragma unroll
    for (int reg = 0; reg < 4; ++reg) {
      int urow = (kg << 2) + reg;
      float v = acc[nb][reg] + bias;
      v = v > 0.f ? v : 0.f;
      wt_[urow * DD + ((((n >> 3) ^ (urow & 7)) << 3) | (n & 7))] = f2bf(v);
    }
  }

  // ---- phase 2b: GEMM2  hout = u @ W2 + b2 ----
  #pragma unroll
  for (int nb = 0; nb < 8; ++nb) acc[nb] = (f32x4){0.f, 0.f, 0.f, 0.f};
  #pragma unroll
  for (int s = 0; s < 4; ++s) {
    ABu au;
    au.q = *(const uint4*)(wt_ + r16 * DD + ((((s << 2) + kg) ^ (r16 & 7)) << 3));
    #pragma unroll
    for (int nb = 0; nb < 8; ++nb) {
      ABu bu; bu.q = *(const uint4*)(w2t + (nb * 16 + r16) * DD + s * 32 + kg * 8);
      acc[nb] = __builtin_amdgcn_mfma_f32_16x16x32_bf16(au.v, bu.v, acc[nb], 0, 0, 0);
    }
  }
  #pragma unroll
  for (int reg = 0; reg < 4; ++reg) {
    int row = waveBase + (kg << 2) + reg;
    if (row < NN) {
      #pragma unroll
      for (int nb = 0; nb < 8; ++nb) {
        int n = nb * 16 + r16;
        hout[row * DD + n] = f2bf(acc[nb][reg] + b2[n]);
      }
    }
  }
}

// ---------------- fused pooling: one block per graph (batch sorted) ----------------
__global__ __launch_bounds__(256) void k_pool(const unsigned short* __restrict__ hb,
                                              const int* __restrict__ batch,
                                              float* __restrict__ out) {
  const int g  = blockIdx.x;
  const int f2 = threadIdx.x & 63;
  const int rp = threadIdx.x >> 6;
  int lo = 0, hi = NN;
  while (lo < hi) { int m = (lo + hi) >> 1; if (batch[m] < g) lo = m + 1; else hi = m; }
  const int start = lo;
  hi = NN;
  while (lo < hi) { int m = (lo + hi) >> 1; if (batch[m] < g + 1) lo = m + 1; else hi = m; }
  const int end = lo;

  const unsigned int* h32 = (const unsigned int*)hb;
  float2 acc = {0.f, 0.f};
  int i = start + rp;
  for (; i + 4 < end; i += 8) {
    float2 a = bfu(h32[(size_t)i * 64 + f2]);
    float2 b = bfu(h32[(size_t)(i + 4) * 64 + f2]);
    acc.x += a.x + b.x; acc.y += a.y + b.y;
  }
  for (; i < end; i += 4) {
    float2 a = bfu(h32[(size_t)i * 64 + f2]);
    acc.x += a.x; acc.y += a.y;
  }

  __shared__ float2 part[4][64];
  part[rp][f2] = acc;
  __syncthreads();
  if (rp == 0) {
    float2 t0 = part[0][f2], t1 = part[1][f2], t2 = part[2][f2], t3 = part[3][f2];
    float inv = 1.0f / (float)max(end - start, 1);
    out[g * DD + 2 * f2]     = (t0.x + t1.x + t2.x + t3.x) * inv;
    out[g * DD + 2 * f2 + 1] = (t0.y + t1.y + t2.y + t3.y) * inv;
  }
}

// ---------------- launch ----------------
extern "C" void kernel_launch(void* const* d_in, const int* in_sizes, int n_in,
                              void* d_out, int out_size, void* d_ws, size_t ws_size,
                              hipStream_t stream) {
  const float* x    = (const float*)d_in[0];
  const int* ei     = (const int*)d_in[1];
  const int* src    = ei;
  const int* dst    = ei + NE;
  const int* batch  = (const int*)d_in[2];

  char* ws = (char*)d_ws;
  size_t off = 0;
  auto alloc = [&](size_t bytes) { char* p = ws + off; off = (off + bytes + 255) & ~(size_t)255; return p; };

  int*  deg    = (int*)alloc(2 * NN * 4);       // deg + cursor contiguous
  int*  cursor = deg + NN;
  int*  rowptr = (int*)alloc((NN + 1) * 4);
  int*  bsum   = (int*)alloc(NBS * 4);
  int*  csr    = (int*)alloc(NE * 4);
  unsigned short* wt = (unsigned short*)alloc(6 * 16384 * 2);
  unsigned short* xb = (unsigned short*)alloc((size_t)NN * DD * 2);
  unsigned short* hA = (unsigned short*)alloc((size_t)NN * DD * 2);
  unsigned short* hB = (unsigned short*)alloc((size_t)NN * DD * 2);

  hipMemsetAsync(deg, 0, 2 * NN * 4, stream);

  k_wconv<<<(6 * 16384 + 255) / 256, 256, 0, stream>>>(
      (const float*)d_in[3], (const float*)d_in[5],
      (const float*)d_in[7], (const float*)d_in[9],
      (const float*)d_in[11], (const float*)d_in[13], wt);
  k_xconv<<<(NN * DD / 4 + 255) / 256, 256, 0, stream>>>(x, xb);

  const int echunks = (NE + 255) / 256;
  k_count<<<8 * echunks, 256, 0, stream>>>(dst, deg);
  k_scanA<<<NBS, 1024, 0, stream>>>(deg, rowptr, bsum);
  k_scanB<<<1, 64, 0, stream>>>(bsum);
  k_scanC<<<NBS, 1024, 0, stream>>>(rowptr, bsum);
  k_fill<<<8 * echunks, 256, 0, stream>>>(src, dst, rowptr, cursor, csr);

  const unsigned short* hin = xb;
  unsigned short* houts[3] = {hA, hB, hA};
  for (int l = 0; l < 3; ++l) {
    k_gin<<<(NN + 15) / 16, 64, 0, stream>>>(
        hin, rowptr, csr,
        wt + (2 * l) * 16384, (const float*)d_in[4 + 4 * l],
        wt + (2 * l + 1) * 16384, (const float*)d_in[6 + 4 * l], houts[l]);
    hin = houts[l];
  }

  k_pool<<<NG, 256, 0, stream>>>(hin, batch, (float*)d_out);
}